// Round 9
// baseline (142.612 us; speedup 1.0000x reference)
//
#include <hip/hip_runtime.h>
#include <hip/hip_fp16.h>
#include <math.h>

// Elastic transform: [32,256,1024,3] fp32, 3x3 control grid displacement.
//   k_disp   : per-(h,w) setup: (dy,dx) + hoisted sampling setup
//              (wy f32x4, parity-shifted wx as 3x half2, 4 byte tap-offsets)
//   k_wfilt  : spline prefilter along W (17-tap mirror FIR, f32 math),
//              x -> 96 fp16 planes [b*3+c][h][w]
//   k_hfilt  : prefilter along H in place (unpack->f32 FIR->repack), uniform
//   k_sample : 4x4 cubic gather; interior = 3 setup loads + 12 f4a tap loads
//              + v_dot2_f32_f16 x-reduction (f32 accumulate); b-fastest grid
//
// fp16 is STORAGE ONLY except dot2 (fp16 multiply, f32 accumulate).

#define H_ 256
#define W_ 1024
#define B_ 32
#define RAD 8                // |z|^9 trunc err ~1e-4 << 2e-2 threshold
#define ROWF 3072            // W_*3 floats per (b,h) row of x
#define HW_ (H_ * W_)        // 262144 pixels per plane
#define HW2 (HW_ / 2)        // dwords per fp16 plane
#define W2 (W_ / 2)          // dwords per fp16 row

typedef float f4a __attribute__((ext_vector_type(4), aligned(4)));
typedef _Float16 h2 __attribute__((ext_vector_type(2)));

#if defined(__has_builtin)
#if __has_builtin(__builtin_amdgcn_fdot2)
#define HAVE_FDOT2 1
#endif
#endif

__device__ __forceinline__ float dot2(float dword, float wgt_dword, float c) {
    h2 a = __builtin_bit_cast(h2, dword);
    h2 b = __builtin_bit_cast(h2, wgt_dword);
#ifdef HAVE_FDOT2
    return __builtin_amdgcn_fdot2(a, b, c, false);
#else
    return (float)a.x * (float)b.x + (float)a.y * (float)b.y + c;
#endif
}

__device__ __forceinline__ float b3f(float t) {
    float a = fabsf(t);
    if (a < 1.0f) return (4.0f - 6.0f * a * a + 3.0f * a * a * a) * (1.0f / 6.0f);
    if (a < 2.0f) { float s = 2.0f - a; return s * s * s * (1.0f / 6.0f); }
    return 0.0f;
}

__device__ __forceinline__ void cubw(float f, float* w) {
    float f2 = f * f, f3 = f2 * f;
    float om = 1.0f - f;
    w[0] = om * om * om * (1.0f / 6.0f);
    w[1] = (3.0f * f3 - 6.0f * f2 + 4.0f) * (1.0f / 6.0f);
    w[2] = (-3.0f * f3 + 3.0f * f2 + 3.0f * f + 1.0f) * (1.0f / 6.0f);
    w[3] = f3 * (1.0f / 6.0f);
}

__device__ __forceinline__ float clamp01(float v) {
    return fminf(fmaxf(v, 0.0f), 1.0f);
}

__device__ __forceinline__ float2 up2(float d) {
    return __half22float2(__builtin_bit_cast(__half2, d));
}
__device__ __forceinline__ float pk2(float a, float b) {
    return __builtin_bit_cast(float, __floats2half2_rn(a, b));
}

__device__ __forceinline__ void basis3(int i, int n, float& w0, float& w1, float& w2) {
    float u = (float)i * 2.0f / (float)(n - 1);
    int base = (int)floorf(u);
    w0 = w1 = w2 = 0.0f;
#pragma unroll
    for (int k = -1; k < 3; ++k) {
        int id = base + k;
        float bw = b3f(u - (float)id);
        int j = id < 0 ? -id : id;
        j &= 3;
        if (j == 3) j = 1;
        if (j == 0) w0 += bw; else if (j == 1) w1 += bw; else w2 += bw;
    }
}

// ---------------- kernel 0: displacement + hoisted sampling setup ---------
__global__ __launch_bounds__(256) void k_disp(const float* __restrict__ disp,
                                              float2* __restrict__ dxy,
                                              float4* __restrict__ sY,
                                              int4* __restrict__ sX,
                                              int4* __restrict__ sO) {
    int idx = blockIdx.x * 256 + threadIdx.x;
    int h = idx >> 10, w = idx & 1023;

    const float A[3][3] = {{1.75f, -1.0f, 0.25f},
                           {-0.5f,  2.0f, -0.5f},
                           {0.25f, -1.0f, 1.75f}};
    float Ty[3][3], Tx[3][3];
#pragma unroll
    for (int i = 0; i < 3; ++i)
#pragma unroll
        for (int j = 0; j < 3; ++j) {
            float ty = 0.f, tx = 0.f;
#pragma unroll
            for (int k = 0; k < 3; ++k) {
                ty += A[i][k] * (5.0f * disp[k * 3 + j]);
                tx += A[i][k] * (5.0f * disp[9 + k * 3 + j]);
            }
            Ty[i][j] = ty; Tx[i][j] = tx;
        }
    float Cy[3][3], Cx[3][3];
#pragma unroll
    for (int i = 0; i < 3; ++i)
#pragma unroll
        for (int j = 0; j < 3; ++j) {
            float ty = 0.f, tx = 0.f;
#pragma unroll
            for (int k = 0; k < 3; ++k) {
                ty += Ty[i][k] * A[j][k];
                tx += Tx[i][k] * A[j][k];
            }
            Cy[i][j] = ty; Cx[i][j] = tx;
        }

    float rh0, rh1, rh2, rw0, rw1, rw2;
    basis3(h, H_, rh0, rh1, rh2);
    basis3(w, W_, rw0, rw1, rw2);
    float rh[3] = {rh0, rh1, rh2}, rw[3] = {rw0, rw1, rw2};

    float dy = 0.f, dx = 0.f;
#pragma unroll
    for (int i = 0; i < 3; ++i)
#pragma unroll
        for (int j = 0; j < 3; ++j) {
            dy += rh[i] * Cy[i][j] * rw[j];
            dx += rh[i] * Cx[i][j] * rw[j];
        }
    dxy[idx] = make_float2(dy, dx);

    // ---- hoisted sampling setup ----
    float cy = (float)h + dy;
    float cx = (float)w + dx;
    float byf = floorf(cy), bxf = floorf(cx);
    int by = (int)byf, bx = (int)bxf;
    float wy[4], wx[4];
    cubw(cy - byf, wy);
    cubw(cx - bxf, wx);

    float4 vy; vy.x = wy[0]; vy.y = wy[1]; vy.z = wy[2]; vy.w = wy[3];
    sY[idx] = vy;

    const bool xin = (bx >= 1) && (bx <= W_ - 6);
    int4 vx, vo;
    if (xin) {
        int bxm1 = bx - 1;
        int bx0 = bxm1 & ~1;
        int par = bxm1 & 1;
        float w6[6] = {0.f, 0.f, 0.f, 0.f, 0.f, 0.f};
#pragma unroll
        for (int k = 0; k < 4; ++k) w6[k + (par ? 1 : 0)] = wx[k];
        vx.x = __builtin_bit_cast(int, pk2(w6[0], w6[1]));
        vx.y = __builtin_bit_cast(int, pk2(w6[2], w6[3]));
        vx.z = __builtin_bit_cast(int, pk2(w6[4], w6[5]));
        vx.w = 0;
#pragma unroll
        for (int r = 0; r < 4; ++r) {
            int iy = min(max(by - 1 + r, 0), H_ - 1);
            ((int*)&vo)[r] = (iy * W_ + bx0) * 2;   // byte offset, 4B-aligned
        }
    } else {
        vx.x = 0; vx.y = 0; vx.z = 0; vx.w = 1;     // fallback flag
        vo.x = 0; vo.y = 0; vo.z = 0; vo.w = 0;
    }
    sX[idx] = vx;
    sO[idx] = vo;
}

// ---------------- kernel 1: prefilter along W, x -> fp16 planes -----------
// per channel LDS: [8 halo][1024][8 halo] = 1040, stride 1040
#define PLN 1040
__global__ __launch_bounds__(256) void k_wfilt(const float* __restrict__ x,
                                               float* __restrict__ coefH) {
    __shared__ float pl[3 * PLN];        // 12480 B
    const int bp = blockIdx.x;           // b*256 + h
    const int t = threadIdx.x;
    const float* row = x + (size_t)bp * ROWF;

    {
        float4 v0 = *(const float4*)(row + 12 * t);
        float4 v1 = *(const float4*)(row + 12 * t + 4);
        float4 v2 = *(const float4*)(row + 12 * t + 8);
        float4 c0, c1, c2;
        c0.x = v0.x; c0.y = v0.w; c0.z = v1.z; c0.w = v2.y;
        c1.x = v0.y; c1.y = v1.x; c1.z = v1.w; c1.w = v2.z;
        c2.x = v0.z; c2.y = v1.y; c2.z = v2.x; c2.w = v2.w;
        *(float4*)(pl + 0 * PLN + 8 + 4 * t) = c0;
        *(float4*)(pl + 1 * PLN + 8 + 4 * t) = c1;
        *(float4*)(pl + 2 * PLN + 8 + 4 * t) = c2;
    }
    __syncthreads();

    if (t < 48) {                        // mirror halos: 3ch x (8 left + 8 right)
        int c = t >> 4, i = t & 15;
        float* p = pl + c * PLN;
        if (i < 8) { int j = i + 1; p[8 - j] = p[8 + j]; }
        else { int r = i - 8; p[1032 + r] = p[1030 - r]; }
    }
    __syncthreads();

    float g[RAD + 1];
    g[0] = 1.7320508075688773f;
#pragma unroll
    for (int k = 1; k <= RAD; ++k) g[k] = g[k - 1] * (-0.26794919243112270647f);

    float res[3][4];
#pragma unroll
    for (int c = 0; c < 3; ++c) {
        const float* p = pl + c * PLN + 4 * t;
        float w[20];
#pragma unroll
        for (int i = 0; i < 5; ++i) {
            float4 v = *(const float4*)(p + 4 * i);
            w[4 * i] = v.x; w[4 * i + 1] = v.y; w[4 * i + 2] = v.z; w[4 * i + 3] = v.w;
        }
#pragma unroll
        for (int j = 0; j < 4; ++j) {
            float a = g[0] * w[j + 8];
#pragma unroll
            for (int k = 1; k <= 8; ++k)
                a += g[k] * (w[j + 8 - k] + w[j + 8 + k]);
            res[c][j] = a;
        }
    }

    const int b = bp >> 8, h = bp & 255;
#pragma unroll
    for (int c = 0; c < 3; ++c) {
        float2 o;
        o.x = pk2(res[c][0], res[c][1]);
        o.y = pk2(res[c][2], res[c][3]);
        *(float2*)(coefH + (size_t)(b * 3 + c) * HW2 + (size_t)h * W2 + 2 * t) = o;
    }
}

// ---------------- kernel 2: prefilter along H, in place, fp16 planes ------
// grid (16, 96): 64-half-wide chunk x plane. LDS tile [256 rows][40 dwords].
#define TSTR 40
__global__ __launch_bounds__(256) void k_hfilt(float* __restrict__ coefH) {
    __shared__ float tile[H_ * TSTR];   // 40 KiB
    const int t = threadIdx.x;
    float* src = coefH + (size_t)blockIdx.y * HW2 + blockIdx.x * 32;

#pragma unroll
    for (int it = 0; it < 8; ++it) {
        int idx = t + it * 256;          // 0..2047 float4s
        int r = idx >> 3, seg = idx & 7;
        *(float4*)(tile + r * TSTR + seg * 4) =
            *(const float4*)(src + (size_t)r * W2 + seg * 4);
    }
    __syncthreads();

    float g[RAD + 1];
    g[0] = 1.7320508075688773f;
#pragma unroll
    for (int k = 1; k <= RAD; ++k) g[k] = g[k - 1] * (-0.26794919243112270647f);

    const int cg = t & 7;          // dword4 column group (8 halves)
    const int prow = t >> 3;       // 0..31
    const int p0 = prow * 8;

    float acc[8][8];
#pragma unroll
    for (int j = 0; j < 8; ++j)
#pragma unroll
        for (int q = 0; q < 8; ++q) acc[j][q] = 0.f;

#pragma unroll
    for (int r = 0; r < 8 + 2 * RAD; ++r) {    // 24 rows
        int hh = p0 - RAD + r;
        int m1 = hh < 0 ? -hh : hh;
        int m2 = 2 * (H_ - 1) - hh;
        int mp = m1 < m2 ? m1 : m2;
        float4 v = *(const float4*)(tile + mp * TSTR + cg * 4);
        float2 u0 = up2(v.x), u1 = up2(v.y), u2 = up2(v.z), u3 = up2(v.w);
        float u[8] = {u0.x, u0.y, u1.x, u1.y, u2.x, u2.y, u3.x, u3.y};
#pragma unroll
        for (int j = 0; j < 8; ++j) {
            const int d = r - RAD - j;
            if (d >= -RAD && d <= RAD) {
                const float wgt = g[d < 0 ? -d : d];
#pragma unroll
                for (int q = 0; q < 8; ++q) acc[j][q] += wgt * u[q];
            }
        }
    }

#pragma unroll
    for (int j = 0; j < 8; ++j) {
        float4 o;
        o.x = pk2(acc[j][0], acc[j][1]);
        o.y = pk2(acc[j][2], acc[j][3]);
        o.z = pk2(acc[j][4], acc[j][5]);
        o.w = pk2(acc[j][6], acc[j][7]);
        *(float4*)(src + (size_t)(p0 + j) * W2 + cg * 4) = o;
    }
}

// ---------------- kernel 3: 4x4 cubic gather ------------------------------
// grid (32, 1024): blockIdx.x = b (fastest -> setup L2 reuse), y = hw chunk.
__global__ __launch_bounds__(256) void k_sample(const float* __restrict__ coefH,
                                                const float2* __restrict__ dxy,
                                                const float4* __restrict__ sY,
                                                const int4* __restrict__ sX,
                                                const int4* __restrict__ sO,
                                                float* __restrict__ out) {
    __shared__ float os[768];
    const int t = threadIdx.x;
    const int b = blockIdx.x;
    const int hw = blockIdx.y * 256 + t;

    const char* cb = (const char*)(coefH + (size_t)(b * 3) * HW2);
    const size_t planeB = (size_t)HW_ * 2;     // bytes per plane

    int4 vx = sX[hw];
    float4 vy = sY[hw];
    float s0, s1, s2;

    if (vx.w == 0) {
        int4 vo = sO[hw];
        const float wxa = __builtin_bit_cast(float, vx.x);
        const float wxb = __builtin_bit_cast(float, vx.y);
        const float wxc = __builtin_bit_cast(float, vx.z);
        const float wyv[4] = {vy.x, vy.y, vy.z, vy.w};
        s0 = s1 = s2 = 0.f;
#pragma unroll
        for (int r = 0; r < 4; ++r) {
            const int o = ((const int*)&vo)[r];
            f4a v0 = *(const f4a*)(cb + o);
            f4a v1 = *(const f4a*)(cb + planeB + o);
            f4a v2 = *(const f4a*)(cb + 2 * planeB + o);
            float d0 = dot2(v0.z, wxc, dot2(v0.y, wxb, dot2(v0.x, wxa, 0.f)));
            float d1 = dot2(v1.z, wxc, dot2(v1.y, wxb, dot2(v1.x, wxa, 0.f)));
            float d2 = dot2(v2.z, wxc, dot2(v2.y, wxb, dot2(v2.x, wxa, 0.f)));
            float wyr = wyv[r];
            s0 += wyr * d0;
            s1 += wyr * d1;
            s2 += wyr * d2;
        }
    } else {
        // fallback: recompute from dxy, scalar half taps with x-clamp
        const int h = hw >> 10, w = hw & 1023;
        float2 d = dxy[hw];
        float cy = (float)h + d.x;
        float cx = (float)w + d.y;
        float byf = floorf(cy), bxf = floorf(cx);
        int by = (int)byf, bx = (int)bxf;
        float wy[4], wx[4];
        cubw(cy - byf, wy);
        cubw(cx - bxf, wx);
        int iyW[4], ix4[4];
#pragma unroll
        for (int r = 0; r < 4; ++r)
            iyW[r] = min(max(by - 1 + r, 0), H_ - 1) * W_;
#pragma unroll
        for (int k = 0; k < 4; ++k)
            ix4[k] = min(max(bx - 1 + k, 0), W_ - 1);
        const __half* h0 = (const __half*)cb;
        const __half* h1 = (const __half*)(cb + planeB);
        const __half* h2p = (const __half*)(cb + 2 * planeB);
        s0 = s1 = s2 = 0.f;
#pragma unroll
        for (int r = 0; r < 4; ++r) {
            float wyr = wy[r];
#pragma unroll
            for (int k = 0; k < 4; ++k) {
                float wk = wyr * wx[k];
                int o = iyW[r] + ix4[k];
                s0 += wk * __half2float(h0[o]);
                s1 += wk * __half2float(h1[o]);
                s2 += wk * __half2float(h2p[o]);
            }
        }
    }

    os[3 * t + 0] = clamp01(s0);
    os[3 * t + 1] = clamp01(s1);
    os[3 * t + 2] = clamp01(s2);
    __syncthreads();

    if (t < 192) {
        float4 v = *(const float4*)(os + 4 * t);
        *(float4*)(out + ((size_t)b * HW_ + (size_t)blockIdx.y * 256) * 3 + 4 * t) = v;
    }
}

extern "C" void kernel_launch(void* const* d_in, const int* in_sizes, int n_in,
                              void* d_out, int out_size, void* d_ws, size_t ws_size,
                              hipStream_t stream) {
    const float* x = (const float*)d_in[0];      // [32,256,1024,3]
    const float* disp = (const float*)d_in[1];   // [2,3,3]
    float* out = (float*)d_out;

    char* ws = (char*)d_ws;
    float* coefH = (float*)ws;                       // 48 MiB: 96 fp16 planes
    float2* dxy = (float2*)(ws + 50331648ull);       // 2 MiB
    float4* sY = (float4*)(ws + 52428800ull);        // 4 MiB
    int4* sX = (int4*)(ws + 56623104ull);            // 4 MiB
    int4* sO = (int4*)(ws + 60817408ull);            // 4 MiB

    k_disp<<<dim3(HW_ / 256), dim3(256), 0, stream>>>(disp, dxy, sY, sX, sO);

    k_wfilt<<<dim3(B_ * H_), dim3(256), 0, stream>>>(x, coefH);

    k_hfilt<<<dim3(W2 / 32, 3 * B_), dim3(256), 0, stream>>>(coefH);

    k_sample<<<dim3(B_, HW_ / 256), dim3(256), 0, stream>>>(coefH, dxy, sY, sX, sO, out);
}

// Round 10
// 125.681 us; speedup vs baseline: 1.1347x; 1.1347x over previous
//
#include <hip/hip_runtime.h>
#include <hip/hip_fp16.h>
#include <math.h>

// Elastic transform: [32,256,1024,3] fp32, 3x3 control grid displacement.
//   k_disp   : dense (dy,dx) float2 field [256,1024] from 3x3 control points
//   k_wfilt  : spline prefilter along W (17-tap mirror FIR, f32 math), x ->
//              p01 (half2 per pixel: c0,c1) + p2 (half per pixel: c2)
//   k_hfilt  : prefilter along H in place, f32 math, uniform half-pair FIR
//   k_sample : 4x4 cubic gather, one thread per (b,h,w), in-register setup
//              (R8 structure — setup hides under gather latency);
//              c2 row via parity-aligned f4a + fdot2 (f32 accumulate)
//
// fp16 is STORAGE ONLY except fdot2 (fp16 multiply, f32 accumulate).

#define H_ 256
#define W_ 1024
#define B_ 32
#define RAD 8                // |z|^9 trunc err ~1e-4 << 2e-2 threshold
#define ROWF 3072            // W_*3 floats per (b,h) row of x
#define HW_ (H_ * W_)        // 262144 pixels per plane
#define HW2 (HW_ / 2)        // dwords per fp16 single-channel plane
#define W2 (W_ / 2)          // dwords per fp16 single-channel row

typedef float f4a __attribute__((ext_vector_type(4), aligned(4)));
typedef _Float16 h2 __attribute__((ext_vector_type(2)));

#if defined(__has_builtin)
#if __has_builtin(__builtin_amdgcn_fdot2)
#define HAVE_FDOT2 1
#endif
#endif

__device__ __forceinline__ float dot2(float dword, float wgt_dword, float c) {
    h2 a = __builtin_bit_cast(h2, dword);
    h2 b = __builtin_bit_cast(h2, wgt_dword);
#ifdef HAVE_FDOT2
    return __builtin_amdgcn_fdot2(a, b, c, false);
#else
    return (float)a.x * (float)b.x + (float)a.y * (float)b.y + c;
#endif
}

__device__ __forceinline__ float b3f(float t) {
    float a = fabsf(t);
    if (a < 1.0f) return (4.0f - 6.0f * a * a + 3.0f * a * a * a) * (1.0f / 6.0f);
    if (a < 2.0f) { float s = 2.0f - a; return s * s * s * (1.0f / 6.0f); }
    return 0.0f;
}

__device__ __forceinline__ void cubw(float f, float* w) {
    float f2 = f * f, f3 = f2 * f;
    float om = 1.0f - f;
    w[0] = om * om * om * (1.0f / 6.0f);
    w[1] = (3.0f * f3 - 6.0f * f2 + 4.0f) * (1.0f / 6.0f);
    w[2] = (-3.0f * f3 + 3.0f * f2 + 3.0f * f + 1.0f) * (1.0f / 6.0f);
    w[3] = f3 * (1.0f / 6.0f);
}

__device__ __forceinline__ float clamp01(float v) {
    return fminf(fmaxf(v, 0.0f), 1.0f);
}

__device__ __forceinline__ float2 up2(float d) {
    return __half22float2(__builtin_bit_cast(__half2, d));
}
__device__ __forceinline__ float pk2(float a, float b) {
    return __builtin_bit_cast(float, __floats2half2_rn(a, b));
}

__device__ __forceinline__ void basis3(int i, int n, float& w0, float& w1, float& w2) {
    float u = (float)i * 2.0f / (float)(n - 1);
    int base = (int)floorf(u);
    w0 = w1 = w2 = 0.0f;
#pragma unroll
    for (int k = -1; k < 3; ++k) {
        int id = base + k;
        float bw = b3f(u - (float)id);
        int j = id < 0 ? -id : id;
        j &= 3;
        if (j == 3) j = 1;
        if (j == 0) w0 += bw; else if (j == 1) w1 += bw; else w2 += bw;
    }
}

// ---------------- kernel 0: displacement field (dy,dx) --------------------
__global__ __launch_bounds__(256) void k_disp(const float* __restrict__ disp,
                                              float2* __restrict__ dxy) {
    int idx = blockIdx.x * 256 + threadIdx.x;
    int h = idx >> 10, w = idx & 1023;

    const float A[3][3] = {{1.75f, -1.0f, 0.25f},
                           {-0.5f,  2.0f, -0.5f},
                           {0.25f, -1.0f, 1.75f}};
    float Ty[3][3], Tx[3][3];
#pragma unroll
    for (int i = 0; i < 3; ++i)
#pragma unroll
        for (int j = 0; j < 3; ++j) {
            float ty = 0.f, tx = 0.f;
#pragma unroll
            for (int k = 0; k < 3; ++k) {
                ty += A[i][k] * (5.0f * disp[k * 3 + j]);
                tx += A[i][k] * (5.0f * disp[9 + k * 3 + j]);
            }
            Ty[i][j] = ty; Tx[i][j] = tx;
        }
    float Cy[3][3], Cx[3][3];
#pragma unroll
    for (int i = 0; i < 3; ++i)
#pragma unroll
        for (int j = 0; j < 3; ++j) {
            float ty = 0.f, tx = 0.f;
#pragma unroll
            for (int k = 0; k < 3; ++k) {
                ty += Ty[i][k] * A[j][k];
                tx += Tx[i][k] * A[j][k];
            }
            Cy[i][j] = ty; Cx[i][j] = tx;
        }

    float rh0, rh1, rh2, rw0, rw1, rw2;
    basis3(h, H_, rh0, rh1, rh2);
    basis3(w, W_, rw0, rw1, rw2);
    float rh[3] = {rh0, rh1, rh2}, rw[3] = {rw0, rw1, rw2};

    float dy = 0.f, dx = 0.f;
#pragma unroll
    for (int i = 0; i < 3; ++i)
#pragma unroll
        for (int j = 0; j < 3; ++j) {
            dy += rh[i] * Cy[i][j] * rw[j];
            dx += rh[i] * Cx[i][j] * rw[j];
        }
    dxy[idx] = make_float2(dy, dx);
}

// ---------------- kernel 1: prefilter along W (f32 math) ------------------
// per channel LDS: [8 halo][1024][8 halo] = 1040, stride 1040
#define PLN 1040
__global__ __launch_bounds__(256) void k_wfilt(const float* __restrict__ x,
                                               float* __restrict__ p01,  // half2/px
                                               float* __restrict__ p2) { // half/px
    __shared__ float pl[3 * PLN];        // 12480 B
    const int bp = blockIdx.x;           // b*256 + h
    const int t = threadIdx.x;
    const float* row = x + (size_t)bp * ROWF;

    {
        float4 v0 = *(const float4*)(row + 12 * t);
        float4 v1 = *(const float4*)(row + 12 * t + 4);
        float4 v2 = *(const float4*)(row + 12 * t + 8);
        float4 c0, c1, c2;
        c0.x = v0.x; c0.y = v0.w; c0.z = v1.z; c0.w = v2.y;
        c1.x = v0.y; c1.y = v1.x; c1.z = v1.w; c1.w = v2.z;
        c2.x = v0.z; c2.y = v1.y; c2.z = v2.x; c2.w = v2.w;
        *(float4*)(pl + 0 * PLN + 8 + 4 * t) = c0;
        *(float4*)(pl + 1 * PLN + 8 + 4 * t) = c1;
        *(float4*)(pl + 2 * PLN + 8 + 4 * t) = c2;
    }
    __syncthreads();

    if (t < 48) {                        // mirror halos: 3ch x (8 left + 8 right)
        int c = t >> 4, i = t & 15;
        float* p = pl + c * PLN;
        if (i < 8) { int j = i + 1; p[8 - j] = p[8 + j]; }
        else { int r = i - 8; p[1032 + r] = p[1030 - r]; }
    }
    __syncthreads();

    float g[RAD + 1];
    g[0] = 1.7320508075688773f;
#pragma unroll
    for (int k = 1; k <= RAD; ++k) g[k] = g[k - 1] * (-0.26794919243112270647f);

    float res[3][4];
#pragma unroll
    for (int c = 0; c < 3; ++c) {
        const float* p = pl + c * PLN + 4 * t;
        float w[20];
#pragma unroll
        for (int i = 0; i < 5; ++i) {
            float4 v = *(const float4*)(p + 4 * i);
            w[4 * i] = v.x; w[4 * i + 1] = v.y; w[4 * i + 2] = v.z; w[4 * i + 3] = v.w;
        }
#pragma unroll
        for (int j = 0; j < 4; ++j) {
            float a = g[0] * w[j + 8];
#pragma unroll
            for (int k = 1; k <= 8; ++k)
                a += g[k] * (w[j + 8 - k] + w[j + 8 + k]);
            res[c][j] = a;
        }
    }

    const int b = bp >> 8, h = bp & 255;
    // p01: one dword per px (c0,c1)
    float4 o01;
    o01.x = pk2(res[0][0], res[1][0]);
    o01.y = pk2(res[0][1], res[1][1]);
    o01.z = pk2(res[0][2], res[1][2]);
    o01.w = pk2(res[0][3], res[1][3]);
    *(float4*)(p01 + (size_t)b * HW_ + (size_t)h * W_ + 4 * t) = o01;
    // p2: one half per px
    float2 o2;
    o2.x = pk2(res[2][0], res[2][1]);
    o2.y = pk2(res[2][2], res[2][3]);
    *(float2*)(p2 + (size_t)b * HW2 + (size_t)h * W2 + 2 * t) = o2;
}

// ---------------- kernel 2: prefilter along H, in place, uniform ----------
// All data is "2 halves per dword": p01 planes are (c0,c1) pairs (row = W_
// dwords, 32 chunks); p2 planes are adjacent-px pairs (row = W2 dwords, 16
// chunks, two planes share a grid row). grid (32, 48).
#define TSTR 40
__global__ __launch_bounds__(256) void k_hfilt(float* __restrict__ p01,
                                               float* __restrict__ p2) {
    __shared__ float tile[H_ * TSTR];   // 40 KiB
    const int t = threadIdx.x;
    const int gy = blockIdx.y;
    float* src;
    int rowdw;
    if (gy < 32) {
        src = p01 + (size_t)gy * HW_ + blockIdx.x * 32;
        rowdw = W_;
    } else {
        int p2i = ((gy - 32) << 1) | (blockIdx.x >> 4);
        src = p2 + (size_t)p2i * HW2 + (blockIdx.x & 15) * 32;
        rowdw = W2;
    }

#pragma unroll
    for (int it = 0; it < 8; ++it) {
        int idx = t + it * 256;          // 0..2047 float4s
        int r = idx >> 3, seg = idx & 7;
        *(float4*)(tile + r * TSTR + seg * 4) =
            *(const float4*)(src + (size_t)r * rowdw + seg * 4);
    }
    __syncthreads();

    float g[RAD + 1];
    g[0] = 1.7320508075688773f;
#pragma unroll
    for (int k = 1; k <= RAD; ++k) g[k] = g[k - 1] * (-0.26794919243112270647f);

    const int cg = t & 7;          // dword4 column group (8 halves)
    const int prow = t >> 3;       // 0..31
    const int p0 = prow * 8;

    float acc[8][8];
#pragma unroll
    for (int j = 0; j < 8; ++j)
#pragma unroll
        for (int q = 0; q < 8; ++q) acc[j][q] = 0.f;

#pragma unroll
    for (int r = 0; r < 8 + 2 * RAD; ++r) {    // 24 rows
        int hh = p0 - RAD + r;
        int m1 = hh < 0 ? -hh : hh;
        int m2 = 2 * (H_ - 1) - hh;
        int mp = m1 < m2 ? m1 : m2;
        float4 v = *(const float4*)(tile + mp * TSTR + cg * 4);
        float2 u0 = up2(v.x), u1 = up2(v.y), u2 = up2(v.z), u3 = up2(v.w);
        float u[8] = {u0.x, u0.y, u1.x, u1.y, u2.x, u2.y, u3.x, u3.y};
#pragma unroll
        for (int j = 0; j < 8; ++j) {
            const int d = r - RAD - j;
            if (d >= -RAD && d <= RAD) {
                const float wgt = g[d < 0 ? -d : d];
#pragma unroll
                for (int q = 0; q < 8; ++q) acc[j][q] += wgt * u[q];
            }
        }
    }

#pragma unroll
    for (int j = 0; j < 8; ++j) {
        float4 o;
        o.x = pk2(acc[j][0], acc[j][1]);
        o.y = pk2(acc[j][2], acc[j][3]);
        o.z = pk2(acc[j][4], acc[j][5]);
        o.w = pk2(acc[j][6], acc[j][7]);
        *(float4*)(src + (size_t)(p0 + j) * rowdw + cg * 4) = o;
    }
}

// ---------------- kernel 3: 4x4 cubic gather, f32 math --------------------
// grid (1024, 32): thread owns one (b, h, w); setup recomputed in-register
// (hides under gather latency — R9 showed memory-hoisting loses).
__global__ __launch_bounds__(256) void k_sample(const float* __restrict__ p01,
                                                const float* __restrict__ p2,
                                                const float2* __restrict__ dxy,
                                                float* __restrict__ out) {
    __shared__ float os[768];
    const int t = threadIdx.x;
    const int hw = blockIdx.x * 256 + t;
    const int b = blockIdx.y;
    const int h = hw >> 10, w = hw & 1023;

    float2 d = dxy[hw];
    float cy = (float)h + d.x;
    float cx = (float)w + d.y;
    float byf = floorf(cy), bxf = floorf(cx);
    int by = (int)byf, bx = (int)bxf;
    float wy[4], wx[4];
    cubw(cy - byf, wy);
    cubw(cx - bxf, wx);

    int iyW[4];
#pragma unroll
    for (int r = 0; r < 4; ++r)
        iyW[r] = min(max(by - 1 + r, 0), H_ - 1) * W_;

    const float* cb01 = p01 + (size_t)b * HW_;
    const __half* cb2h = (const __half*)p2 + (size_t)b * HW_;
    float s0 = 0.f, s1 = 0.f, s2 = 0.f;

    if (bx >= 1 && bx <= W_ - 6) {
        // parity-shifted packed weights for the c2 half rows
        const int bx0 = (bx - 1) & ~1;
        const int par = (bx - 1) & 1;
        float w6[6] = {0.f, 0.f, 0.f, 0.f, 0.f, 0.f};
#pragma unroll
        for (int k = 0; k < 4; ++k) w6[k + (par ? 1 : 0)] = wx[k];
        const float wxa = pk2(w6[0], w6[1]);
        const float wxb = pk2(w6[2], w6[3]);
        const float wxc = pk2(w6[4], w6[5]);

#pragma unroll
        for (int r = 0; r < 4; ++r) {
            int o = iyW[r] + bx - 1;
            f4a v01 = *(const f4a*)(cb01 + o);
            f4a v2 = *(const f4a*)(cb2h + (iyW[r] + bx0));
            float2 u0 = up2(v01.x), u1 = up2(v01.y), u2 = up2(v01.z), u3 = up2(v01.w);
            float wyr = wy[r];
            s0 += wyr * (wx[0] * u0.x + wx[1] * u1.x + wx[2] * u2.x + wx[3] * u3.x);
            s1 += wyr * (wx[0] * u0.y + wx[1] * u1.y + wx[2] * u2.y + wx[3] * u3.y);
            float d2 = dot2(v2.z, wxc, dot2(v2.y, wxb, dot2(v2.x, wxa, 0.f)));
            s2 += wyr * d2;
        }
    } else {
        int ix4[4];
#pragma unroll
        for (int k = 0; k < 4; ++k) ix4[k] = min(max(bx - 1 + k, 0), W_ - 1);
#pragma unroll
        for (int r = 0; r < 4; ++r) {
            float wyr = wy[r];
#pragma unroll
            for (int k = 0; k < 4; ++k) {
                float wk = wyr * wx[k];
                int o = iyW[r] + ix4[k];
                float2 u = up2(cb01[o]);
                s0 += wk * u.x;
                s1 += wk * u.y;
                s2 += wk * __half2float(cb2h[o]);
            }
        }
    }

    os[3 * t + 0] = clamp01(s0);
    os[3 * t + 1] = clamp01(s1);
    os[3 * t + 2] = clamp01(s2);
    __syncthreads();

    if (t < 192) {
        float4 v = *(const float4*)(os + 4 * t);
        *(float4*)(out + ((size_t)b * HW_ + (size_t)blockIdx.x * 256) * 3 + 4 * t) = v;
    }
}

extern "C" void kernel_launch(void* const* d_in, const int* in_sizes, int n_in,
                              void* d_out, int out_size, void* d_ws, size_t ws_size,
                              hipStream_t stream) {
    const float* x = (const float*)d_in[0];      // [32,256,1024,3]
    const float* disp = (const float*)d_in[1];   // [2,3,3]
    float* out = (float*)d_out;

    char* ws = (char*)d_ws;
    float* p01 = (float*)ws;                       // 32 MiB (half2 per pixel)
    float* p2 = (float*)(ws + 33554432ull);        // 16 MiB (half c2)
    float2* dxy = (float2*)(ws + 50331648ull);     // 2 MiB

    k_disp<<<dim3(HW_ / 256), dim3(256), 0, stream>>>(disp, dxy);

    k_wfilt<<<dim3(B_ * H_), dim3(256), 0, stream>>>(x, p01, p2);

    k_hfilt<<<dim3(32, 48), dim3(256), 0, stream>>>(p01, p2);

    k_sample<<<dim3(HW_ / 256, B_), dim3(256), 0, stream>>>(p01, p2, dxy, out);
}

// Round 11
// 116.080 us; speedup vs baseline: 1.2286x; 1.0827x over previous
//
#include <hip/hip_runtime.h>
#include <hip/hip_fp16.h>
#include <math.h>

// Elastic transform: [32,256,1024,3] fp32, 3x3 control grid displacement.
//   k_disp   : dense (dy,dx) float2 field [256,1024] from 3x3 control points
//   k_wfilt  : spline prefilter along W (17-tap mirror FIR, f32 math), x ->
//              p01 (half2 per pixel: c0,c1) + p2 (half per pixel: c2)
//   k_hfilt  : prefilter along H in place, f32 math, uniform half-pair FIR
//   k_sample : 4x4 cubic gather, one thread per (b,h,w), in-register setup;
//              c0/c1 taps via v_fma_mix (fmaf((float)h16,...) peephole) —
//              no unpack cvts; c2 via parity-aligned f4a + fdot2 (f32 acc)
//
// fp16 is STORAGE ONLY except fdot2 (fp16 multiply, f32 accumulate).

#define H_ 256
#define W_ 1024
#define B_ 32
#define RAD 8                // |z|^9 trunc err ~1e-4 << 2e-2 threshold
#define ROWF 3072            // W_*3 floats per (b,h) row of x
#define HW_ (H_ * W_)        // 262144 pixels per plane
#define HW2 (HW_ / 2)        // dwords per fp16 single-channel plane
#define W2 (W_ / 2)          // dwords per fp16 single-channel row

typedef float f4a __attribute__((ext_vector_type(4), aligned(4)));
typedef _Float16 h2 __attribute__((ext_vector_type(2)));
typedef _Float16 h8a __attribute__((ext_vector_type(8), aligned(4)));

#if defined(__has_builtin)
#if __has_builtin(__builtin_amdgcn_fdot2)
#define HAVE_FDOT2 1
#endif
#endif

__device__ __forceinline__ float dot2(float dword, float wgt_dword, float c) {
    h2 a = __builtin_bit_cast(h2, dword);
    h2 b = __builtin_bit_cast(h2, wgt_dword);
#ifdef HAVE_FDOT2
    return __builtin_amdgcn_fdot2(a, b, c, false);
#else
    return (float)a.x * (float)b.x + (float)a.y * (float)b.y + c;
#endif
}

__device__ __forceinline__ float b3f(float t) {
    float a = fabsf(t);
    if (a < 1.0f) return (4.0f - 6.0f * a * a + 3.0f * a * a * a) * (1.0f / 6.0f);
    if (a < 2.0f) { float s = 2.0f - a; return s * s * s * (1.0f / 6.0f); }
    return 0.0f;
}

__device__ __forceinline__ void cubw(float f, float* w) {
    float f2 = f * f, f3 = f2 * f;
    float om = 1.0f - f;
    w[0] = om * om * om * (1.0f / 6.0f);
    w[1] = (3.0f * f3 - 6.0f * f2 + 4.0f) * (1.0f / 6.0f);
    w[2] = (-3.0f * f3 + 3.0f * f2 + 3.0f * f + 1.0f) * (1.0f / 6.0f);
    w[3] = f3 * (1.0f / 6.0f);
}

__device__ __forceinline__ float clamp01(float v) {
    return fminf(fmaxf(v, 0.0f), 1.0f);
}

__device__ __forceinline__ float2 up2(float d) {
    return __half22float2(__builtin_bit_cast(__half2, d));
}
__device__ __forceinline__ float pk2(float a, float b) {
    return __builtin_bit_cast(float, __floats2half2_rn(a, b));
}

__device__ __forceinline__ void basis3(int i, int n, float& w0, float& w1, float& w2) {
    float u = (float)i * 2.0f / (float)(n - 1);
    int base = (int)floorf(u);
    w0 = w1 = w2 = 0.0f;
#pragma unroll
    for (int k = -1; k < 3; ++k) {
        int id = base + k;
        float bw = b3f(u - (float)id);
        int j = id < 0 ? -id : id;
        j &= 3;
        if (j == 3) j = 1;
        if (j == 0) w0 += bw; else if (j == 1) w1 += bw; else w2 += bw;
    }
}

// ---------------- kernel 0: displacement field (dy,dx) --------------------
__global__ __launch_bounds__(256) void k_disp(const float* __restrict__ disp,
                                              float2* __restrict__ dxy) {
    int idx = blockIdx.x * 256 + threadIdx.x;
    int h = idx >> 10, w = idx & 1023;

    const float A[3][3] = {{1.75f, -1.0f, 0.25f},
                           {-0.5f,  2.0f, -0.5f},
                           {0.25f, -1.0f, 1.75f}};
    float Ty[3][3], Tx[3][3];
#pragma unroll
    for (int i = 0; i < 3; ++i)
#pragma unroll
        for (int j = 0; j < 3; ++j) {
            float ty = 0.f, tx = 0.f;
#pragma unroll
            for (int k = 0; k < 3; ++k) {
                ty += A[i][k] * (5.0f * disp[k * 3 + j]);
                tx += A[i][k] * (5.0f * disp[9 + k * 3 + j]);
            }
            Ty[i][j] = ty; Tx[i][j] = tx;
        }
    float Cy[3][3], Cx[3][3];
#pragma unroll
    for (int i = 0; i < 3; ++i)
#pragma unroll
        for (int j = 0; j < 3; ++j) {
            float ty = 0.f, tx = 0.f;
#pragma unroll
            for (int k = 0; k < 3; ++k) {
                ty += Ty[i][k] * A[j][k];
                tx += Tx[i][k] * A[j][k];
            }
            Cy[i][j] = ty; Cx[i][j] = tx;
        }

    float rh0, rh1, rh2, rw0, rw1, rw2;
    basis3(h, H_, rh0, rh1, rh2);
    basis3(w, W_, rw0, rw1, rw2);
    float rh[3] = {rh0, rh1, rh2}, rw[3] = {rw0, rw1, rw2};

    float dy = 0.f, dx = 0.f;
#pragma unroll
    for (int i = 0; i < 3; ++i)
#pragma unroll
        for (int j = 0; j < 3; ++j) {
            dy += rh[i] * Cy[i][j] * rw[j];
            dx += rh[i] * Cx[i][j] * rw[j];
        }
    dxy[idx] = make_float2(dy, dx);
}

// ---------------- kernel 1: prefilter along W (f32 math) ------------------
// per channel LDS: [8 halo][1024][8 halo] = 1040, stride 1040
#define PLN 1040
__global__ __launch_bounds__(256) void k_wfilt(const float* __restrict__ x,
                                               float* __restrict__ p01,  // half2/px
                                               float* __restrict__ p2) { // half/px
    __shared__ float pl[3 * PLN];        // 12480 B
    const int bp = blockIdx.x;           // b*256 + h
    const int t = threadIdx.x;
    const float* row = x + (size_t)bp * ROWF;

    {
        float4 v0 = *(const float4*)(row + 12 * t);
        float4 v1 = *(const float4*)(row + 12 * t + 4);
        float4 v2 = *(const float4*)(row + 12 * t + 8);
        float4 c0, c1, c2;
        c0.x = v0.x; c0.y = v0.w; c0.z = v1.z; c0.w = v2.y;
        c1.x = v0.y; c1.y = v1.x; c1.z = v1.w; c1.w = v2.z;
        c2.x = v0.z; c2.y = v1.y; c2.z = v2.x; c2.w = v2.w;
        *(float4*)(pl + 0 * PLN + 8 + 4 * t) = c0;
        *(float4*)(pl + 1 * PLN + 8 + 4 * t) = c1;
        *(float4*)(pl + 2 * PLN + 8 + 4 * t) = c2;
    }
    __syncthreads();

    if (t < 48) {                        // mirror halos: 3ch x (8 left + 8 right)
        int c = t >> 4, i = t & 15;
        float* p = pl + c * PLN;
        if (i < 8) { int j = i + 1; p[8 - j] = p[8 + j]; }
        else { int r = i - 8; p[1032 + r] = p[1030 - r]; }
    }
    __syncthreads();

    float g[RAD + 1];
    g[0] = 1.7320508075688773f;
#pragma unroll
    for (int k = 1; k <= RAD; ++k) g[k] = g[k - 1] * (-0.26794919243112270647f);

    float res[3][4];
#pragma unroll
    for (int c = 0; c < 3; ++c) {
        const float* p = pl + c * PLN + 4 * t;
        float w[20];
#pragma unroll
        for (int i = 0; i < 5; ++i) {
            float4 v = *(const float4*)(p + 4 * i);
            w[4 * i] = v.x; w[4 * i + 1] = v.y; w[4 * i + 2] = v.z; w[4 * i + 3] = v.w;
        }
#pragma unroll
        for (int j = 0; j < 4; ++j) {
            float a = g[0] * w[j + 8];
#pragma unroll
            for (int k = 1; k <= 8; ++k)
                a += g[k] * (w[j + 8 - k] + w[j + 8 + k]);
            res[c][j] = a;
        }
    }

    const int b = bp >> 8, h = bp & 255;
    float4 o01;
    o01.x = pk2(res[0][0], res[1][0]);
    o01.y = pk2(res[0][1], res[1][1]);
    o01.z = pk2(res[0][2], res[1][2]);
    o01.w = pk2(res[0][3], res[1][3]);
    *(float4*)(p01 + (size_t)b * HW_ + (size_t)h * W_ + 4 * t) = o01;
    float2 o2;
    o2.x = pk2(res[2][0], res[2][1]);
    o2.y = pk2(res[2][2], res[2][3]);
    *(float2*)(p2 + (size_t)b * HW2 + (size_t)h * W2 + 2 * t) = o2;
}

// ---------------- kernel 2: prefilter along H, in place, uniform ----------
// grid (32, 48): p01 planes (32 rows-of-grid) + p2 planes (16, paired).
#define TSTR 40
__global__ __launch_bounds__(256) void k_hfilt(float* __restrict__ p01,
                                               float* __restrict__ p2) {
    __shared__ float tile[H_ * TSTR];   // 40 KiB
    const int t = threadIdx.x;
    const int gy = blockIdx.y;
    float* src;
    int rowdw;
    if (gy < 32) {
        src = p01 + (size_t)gy * HW_ + blockIdx.x * 32;
        rowdw = W_;
    } else {
        int p2i = ((gy - 32) << 1) | (blockIdx.x >> 4);
        src = p2 + (size_t)p2i * HW2 + (blockIdx.x & 15) * 32;
        rowdw = W2;
    }

#pragma unroll
    for (int it = 0; it < 8; ++it) {
        int idx = t + it * 256;          // 0..2047 float4s
        int r = idx >> 3, seg = idx & 7;
        *(float4*)(tile + r * TSTR + seg * 4) =
            *(const float4*)(src + (size_t)r * rowdw + seg * 4);
    }
    __syncthreads();

    float g[RAD + 1];
    g[0] = 1.7320508075688773f;
#pragma unroll
    for (int k = 1; k <= RAD; ++k) g[k] = g[k - 1] * (-0.26794919243112270647f);

    const int cg = t & 7;          // dword4 column group (8 halves)
    const int prow = t >> 3;       // 0..31
    const int p0 = prow * 8;

    float acc[8][8];
#pragma unroll
    for (int j = 0; j < 8; ++j)
#pragma unroll
        for (int q = 0; q < 8; ++q) acc[j][q] = 0.f;

#pragma unroll
    for (int r = 0; r < 8 + 2 * RAD; ++r) {    // 24 rows
        int hh = p0 - RAD + r;
        int m1 = hh < 0 ? -hh : hh;
        int m2 = 2 * (H_ - 1) - hh;
        int mp = m1 < m2 ? m1 : m2;
        float4 v = *(const float4*)(tile + mp * TSTR + cg * 4);
        float2 u0 = up2(v.x), u1 = up2(v.y), u2 = up2(v.z), u3 = up2(v.w);
        float u[8] = {u0.x, u0.y, u1.x, u1.y, u2.x, u2.y, u3.x, u3.y};
#pragma unroll
        for (int j = 0; j < 8; ++j) {
            const int d = r - RAD - j;
            if (d >= -RAD && d <= RAD) {
                const float wgt = g[d < 0 ? -d : d];
#pragma unroll
                for (int q = 0; q < 8; ++q) acc[j][q] += wgt * u[q];
            }
        }
    }

#pragma unroll
    for (int j = 0; j < 8; ++j) {
        float4 o;
        o.x = pk2(acc[j][0], acc[j][1]);
        o.y = pk2(acc[j][2], acc[j][3]);
        o.z = pk2(acc[j][4], acc[j][5]);
        o.w = pk2(acc[j][6], acc[j][7]);
        *(float4*)(src + (size_t)(p0 + j) * rowdw + cg * 4) = o;
    }
}

// ---------------- kernel 3: 4x4 cubic gather, f32 math --------------------
// grid (1024, 32): thread owns one (b, h, w); setup in-register.
// c0/c1 taps: fmaf((float)h16, w, acc) -> v_fma_mix_f32 (no unpack cvts).
__global__ __launch_bounds__(256) void k_sample(const float* __restrict__ p01,
                                                const float* __restrict__ p2,
                                                const float2* __restrict__ dxy,
                                                float* __restrict__ out) {
    __shared__ float os[768];
    const int t = threadIdx.x;
    const int hw = blockIdx.x * 256 + t;
    const int b = blockIdx.y;
    const int h = hw >> 10, w = hw & 1023;

    float2 d = dxy[hw];
    float cy = (float)h + d.x;
    float cx = (float)w + d.y;
    float byf = floorf(cy), bxf = floorf(cx);
    int by = (int)byf, bx = (int)bxf;
    float wy[4], wx[4];
    cubw(cy - byf, wy);
    cubw(cx - bxf, wx);

    int iyW[4];
#pragma unroll
    for (int r = 0; r < 4; ++r)
        iyW[r] = min(max(by - 1 + r, 0), H_ - 1) * W_;

    const float* cb01 = p01 + (size_t)b * HW_;
    const __half* cb2h = (const __half*)p2 + (size_t)b * HW_;
    float s0 = 0.f, s1 = 0.f, s2 = 0.f;

    if (bx >= 1 && bx <= W_ - 6) {
        // parity-shifted packed weights for the c2 half rows
        const int bx0 = (bx - 1) & ~1;
        const int par = (bx - 1) & 1;
        float w6[6] = {0.f, 0.f, 0.f, 0.f, 0.f, 0.f};
#pragma unroll
        for (int k = 0; k < 4; ++k) w6[k + (par ? 1 : 0)] = wx[k];
        const float wxa = pk2(w6[0], w6[1]);
        const float wxb = pk2(w6[2], w6[3]);
        const float wxc = pk2(w6[4], w6[5]);

#pragma unroll
        for (int r = 0; r < 4; ++r) {
            int o = iyW[r] + bx - 1;
            // 8 halves: c0,c1 interleaved for px bx-1..bx+2
            h8a v = *(const h8a*)(cb01 + o);
            f4a v2 = *(const f4a*)(cb2h + (iyW[r] + bx0));
            float t0 = 0.f, t1 = 0.f;
            t0 = fmaf((float)v[0], wx[0], t0);
            t1 = fmaf((float)v[1], wx[0], t1);
            t0 = fmaf((float)v[2], wx[1], t0);
            t1 = fmaf((float)v[3], wx[1], t1);
            t0 = fmaf((float)v[4], wx[2], t0);
            t1 = fmaf((float)v[5], wx[2], t1);
            t0 = fmaf((float)v[6], wx[3], t0);
            t1 = fmaf((float)v[7], wx[3], t1);
            float wyr = wy[r];
            s0 = fmaf(wyr, t0, s0);
            s1 = fmaf(wyr, t1, s1);
            float d2 = dot2(v2.z, wxc, dot2(v2.y, wxb, dot2(v2.x, wxa, 0.f)));
            s2 = fmaf(wyr, d2, s2);
        }
    } else {
        int ix4[4];
#pragma unroll
        for (int k = 0; k < 4; ++k) ix4[k] = min(max(bx - 1 + k, 0), W_ - 1);
#pragma unroll
        for (int r = 0; r < 4; ++r) {
            float wyr = wy[r];
#pragma unroll
            for (int k = 0; k < 4; ++k) {
                float wk = wyr * wx[k];
                int o = iyW[r] + ix4[k];
                float2 u = up2(cb01[o]);
                s0 += wk * u.x;
                s1 += wk * u.y;
                s2 += wk * __half2float(cb2h[o]);
            }
        }
    }

    os[3 * t + 0] = clamp01(s0);
    os[3 * t + 1] = clamp01(s1);
    os[3 * t + 2] = clamp01(s2);
    __syncthreads();

    if (t < 192) {
        float4 v = *(const float4*)(os + 4 * t);
        *(float4*)(out + ((size_t)b * HW_ + (size_t)blockIdx.x * 256) * 3 + 4 * t) = v;
    }
}

extern "C" void kernel_launch(void* const* d_in, const int* in_sizes, int n_in,
                              void* d_out, int out_size, void* d_ws, size_t ws_size,
                              hipStream_t stream) {
    const float* x = (const float*)d_in[0];      // [32,256,1024,3]
    const float* disp = (const float*)d_in[1];   // [2,3,3]
    float* out = (float*)d_out;

    char* ws = (char*)d_ws;
    float* p01 = (float*)ws;                       // 32 MiB (half2 per pixel)
    float* p2 = (float*)(ws + 33554432ull);        // 16 MiB (half c2)
    float2* dxy = (float2*)(ws + 50331648ull);     // 2 MiB

    k_disp<<<dim3(HW_ / 256), dim3(256), 0, stream>>>(disp, dxy);

    k_wfilt<<<dim3(B_ * H_), dim3(256), 0, stream>>>(x, p01, p2);

    k_hfilt<<<dim3(32, 48), dim3(256), 0, stream>>>(p01, p2);

    k_sample<<<dim3(HW_ / 256, B_), dim3(256), 0, stream>>>(p01, p2, dxy, out);
}

// Round 12
// 113.060 us; speedup vs baseline: 1.2614x; 1.0267x over previous
//
#include <hip/hip_runtime.h>
#include <hip/hip_fp16.h>
#include <math.h>

// Elastic transform: [32,256,1024,3] fp32, 3x3 control grid displacement.
//   k_disp   : dense (dy,dx) float2 field [256,1024] from 3x3 control points
//   k_wfilt  : spline prefilter along W (17-tap mirror FIR, f32 math), x ->
//              p01 (half2 per pixel: c0,c1) + p2 (half per pixel: c2)
//   k_hfilt  : prefilter along H in place, f32 math, uniform half-pair FIR
//   k_sample : 4x4 cubic gather, one thread per (h,w) x TWO batches (b,b+16):
//              setup/weights/offsets/LDS-epilogue amortized across both;
//              c0/c1 taps via v_fma_mix, c2 via parity-aligned fdot2 (f32 acc);
//              branchless select weight-packing (no runtime-indexed arrays)
//
// fp16 is STORAGE ONLY except fdot2 (fp16 multiply, f32 accumulate).

#define H_ 256
#define W_ 1024
#define B_ 32
#define RAD 8                // |z|^9 trunc err ~1e-4 << 2e-2 threshold
#define ROWF 3072            // W_*3 floats per (b,h) row of x
#define HW_ (H_ * W_)        // 262144 pixels per plane
#define HW2 (HW_ / 2)        // dwords per fp16 single-channel plane
#define W2 (W_ / 2)          // dwords per fp16 single-channel row

typedef float f4a __attribute__((ext_vector_type(4), aligned(4)));
typedef _Float16 h2 __attribute__((ext_vector_type(2)));
typedef _Float16 h8a __attribute__((ext_vector_type(8), aligned(4)));

#if defined(__has_builtin)
#if __has_builtin(__builtin_amdgcn_fdot2)
#define HAVE_FDOT2 1
#endif
#endif

__device__ __forceinline__ float dot2(float dword, float wgt_dword, float c) {
    h2 a = __builtin_bit_cast(h2, dword);
    h2 b = __builtin_bit_cast(h2, wgt_dword);
#ifdef HAVE_FDOT2
    return __builtin_amdgcn_fdot2(a, b, c, false);
#else
    return (float)a.x * (float)b.x + (float)a.y * (float)b.y + c;
#endif
}

__device__ __forceinline__ float b3f(float t) {
    float a = fabsf(t);
    if (a < 1.0f) return (4.0f - 6.0f * a * a + 3.0f * a * a * a) * (1.0f / 6.0f);
    if (a < 2.0f) { float s = 2.0f - a; return s * s * s * (1.0f / 6.0f); }
    return 0.0f;
}

__device__ __forceinline__ void cubw(float f, float* w) {
    float f2 = f * f, f3 = f2 * f;
    float om = 1.0f - f;
    w[0] = om * om * om * (1.0f / 6.0f);
    w[1] = (3.0f * f3 - 6.0f * f2 + 4.0f) * (1.0f / 6.0f);
    w[2] = (-3.0f * f3 + 3.0f * f2 + 3.0f * f + 1.0f) * (1.0f / 6.0f);
    w[3] = f3 * (1.0f / 6.0f);
}

__device__ __forceinline__ float clamp01(float v) {
    return fminf(fmaxf(v, 0.0f), 1.0f);
}

__device__ __forceinline__ float2 up2(float d) {
    return __half22float2(__builtin_bit_cast(__half2, d));
}
__device__ __forceinline__ float pk2(float a, float b) {
    return __builtin_bit_cast(float, __floats2half2_rn(a, b));
}

__device__ __forceinline__ void basis3(int i, int n, float& w0, float& w1, float& w2) {
    float u = (float)i * 2.0f / (float)(n - 1);
    int base = (int)floorf(u);
    w0 = w1 = w2 = 0.0f;
#pragma unroll
    for (int k = -1; k < 3; ++k) {
        int id = base + k;
        float bw = b3f(u - (float)id);
        int j = id < 0 ? -id : id;
        j &= 3;
        if (j == 3) j = 1;
        if (j == 0) w0 += bw; else if (j == 1) w1 += bw; else w2 += bw;
    }
}

// ---------------- kernel 0: displacement field (dy,dx) --------------------
__global__ __launch_bounds__(256) void k_disp(const float* __restrict__ disp,
                                              float2* __restrict__ dxy) {
    int idx = blockIdx.x * 256 + threadIdx.x;
    int h = idx >> 10, w = idx & 1023;

    const float A[3][3] = {{1.75f, -1.0f, 0.25f},
                           {-0.5f,  2.0f, -0.5f},
                           {0.25f, -1.0f, 1.75f}};
    float Ty[3][3], Tx[3][3];
#pragma unroll
    for (int i = 0; i < 3; ++i)
#pragma unroll
        for (int j = 0; j < 3; ++j) {
            float ty = 0.f, tx = 0.f;
#pragma unroll
            for (int k = 0; k < 3; ++k) {
                ty += A[i][k] * (5.0f * disp[k * 3 + j]);
                tx += A[i][k] * (5.0f * disp[9 + k * 3 + j]);
            }
            Ty[i][j] = ty; Tx[i][j] = tx;
        }
    float Cy[3][3], Cx[3][3];
#pragma unroll
    for (int i = 0; i < 3; ++i)
#pragma unroll
        for (int j = 0; j < 3; ++j) {
            float ty = 0.f, tx = 0.f;
#pragma unroll
            for (int k = 0; k < 3; ++k) {
                ty += Ty[i][k] * A[j][k];
                tx += Tx[i][k] * A[j][k];
            }
            Cy[i][j] = ty; Cx[i][j] = tx;
        }

    float rh0, rh1, rh2, rw0, rw1, rw2;
    basis3(h, H_, rh0, rh1, rh2);
    basis3(w, W_, rw0, rw1, rw2);
    float rh[3] = {rh0, rh1, rh2}, rw[3] = {rw0, rw1, rw2};

    float dy = 0.f, dx = 0.f;
#pragma unroll
    for (int i = 0; i < 3; ++i)
#pragma unroll
        for (int j = 0; j < 3; ++j) {
            dy += rh[i] * Cy[i][j] * rw[j];
            dx += rh[i] * Cx[i][j] * rw[j];
        }
    dxy[idx] = make_float2(dy, dx);
}

// ---------------- kernel 1: prefilter along W (f32 math) ------------------
// per channel LDS: [8 halo][1024][8 halo] = 1040, stride 1040
#define PLN 1040
__global__ __launch_bounds__(256) void k_wfilt(const float* __restrict__ x,
                                               float* __restrict__ p01,  // half2/px
                                               float* __restrict__ p2) { // half/px
    __shared__ float pl[3 * PLN];        // 12480 B
    const int bp = blockIdx.x;           // b*256 + h
    const int t = threadIdx.x;
    const float* row = x + (size_t)bp * ROWF;

    {
        float4 v0 = *(const float4*)(row + 12 * t);
        float4 v1 = *(const float4*)(row + 12 * t + 4);
        float4 v2 = *(const float4*)(row + 12 * t + 8);
        float4 c0, c1, c2;
        c0.x = v0.x; c0.y = v0.w; c0.z = v1.z; c0.w = v2.y;
        c1.x = v0.y; c1.y = v1.x; c1.z = v1.w; c1.w = v2.z;
        c2.x = v0.z; c2.y = v1.y; c2.z = v2.x; c2.w = v2.w;
        *(float4*)(pl + 0 * PLN + 8 + 4 * t) = c0;
        *(float4*)(pl + 1 * PLN + 8 + 4 * t) = c1;
        *(float4*)(pl + 2 * PLN + 8 + 4 * t) = c2;
    }
    __syncthreads();

    if (t < 48) {                        // mirror halos: 3ch x (8 left + 8 right)
        int c = t >> 4, i = t & 15;
        float* p = pl + c * PLN;
        if (i < 8) { int j = i + 1; p[8 - j] = p[8 + j]; }
        else { int r = i - 8; p[1032 + r] = p[1030 - r]; }
    }
    __syncthreads();

    float g[RAD + 1];
    g[0] = 1.7320508075688773f;
#pragma unroll
    for (int k = 1; k <= RAD; ++k) g[k] = g[k - 1] * (-0.26794919243112270647f);

    float res[3][4];
#pragma unroll
    for (int c = 0; c < 3; ++c) {
        const float* p = pl + c * PLN + 4 * t;
        float w[20];
#pragma unroll
        for (int i = 0; i < 5; ++i) {
            float4 v = *(const float4*)(p + 4 * i);
            w[4 * i] = v.x; w[4 * i + 1] = v.y; w[4 * i + 2] = v.z; w[4 * i + 3] = v.w;
        }
#pragma unroll
        for (int j = 0; j < 4; ++j) {
            float a = g[0] * w[j + 8];
#pragma unroll
            for (int k = 1; k <= 8; ++k)
                a += g[k] * (w[j + 8 - k] + w[j + 8 + k]);
            res[c][j] = a;
        }
    }

    const int b = bp >> 8, h = bp & 255;
    float4 o01;
    o01.x = pk2(res[0][0], res[1][0]);
    o01.y = pk2(res[0][1], res[1][1]);
    o01.z = pk2(res[0][2], res[1][2]);
    o01.w = pk2(res[0][3], res[1][3]);
    *(float4*)(p01 + (size_t)b * HW_ + (size_t)h * W_ + 4 * t) = o01;
    float2 o2;
    o2.x = pk2(res[2][0], res[2][1]);
    o2.y = pk2(res[2][2], res[2][3]);
    *(float2*)(p2 + (size_t)b * HW2 + (size_t)h * W2 + 2 * t) = o2;
}

// ---------------- kernel 2: prefilter along H, in place, uniform ----------
// grid (32, 48): p01 planes (32 rows-of-grid) + p2 planes (16, paired).
#define TSTR 40
__global__ __launch_bounds__(256) void k_hfilt(float* __restrict__ p01,
                                               float* __restrict__ p2) {
    __shared__ float tile[H_ * TSTR];   // 40 KiB
    const int t = threadIdx.x;
    const int gy = blockIdx.y;
    float* src;
    int rowdw;
    if (gy < 32) {
        src = p01 + (size_t)gy * HW_ + blockIdx.x * 32;
        rowdw = W_;
    } else {
        int p2i = ((gy - 32) << 1) | (blockIdx.x >> 4);
        src = p2 + (size_t)p2i * HW2 + (blockIdx.x & 15) * 32;
        rowdw = W2;
    }

#pragma unroll
    for (int it = 0; it < 8; ++it) {
        int idx = t + it * 256;          // 0..2047 float4s
        int r = idx >> 3, seg = idx & 7;
        *(float4*)(tile + r * TSTR + seg * 4) =
            *(const float4*)(src + (size_t)r * rowdw + seg * 4);
    }
    __syncthreads();

    float g[RAD + 1];
    g[0] = 1.7320508075688773f;
#pragma unroll
    for (int k = 1; k <= RAD; ++k) g[k] = g[k - 1] * (-0.26794919243112270647f);

    const int cg = t & 7;          // dword4 column group (8 halves)
    const int prow = t >> 3;       // 0..31
    const int p0 = prow * 8;

    float acc[8][8];
#pragma unroll
    for (int j = 0; j < 8; ++j)
#pragma unroll
        for (int q = 0; q < 8; ++q) acc[j][q] = 0.f;

#pragma unroll
    for (int r = 0; r < 8 + 2 * RAD; ++r) {    // 24 rows
        int hh = p0 - RAD + r;
        int m1 = hh < 0 ? -hh : hh;
        int m2 = 2 * (H_ - 1) - hh;
        int mp = m1 < m2 ? m1 : m2;
        float4 v = *(const float4*)(tile + mp * TSTR + cg * 4);
        float2 u0 = up2(v.x), u1 = up2(v.y), u2 = up2(v.z), u3 = up2(v.w);
        float u[8] = {u0.x, u0.y, u1.x, u1.y, u2.x, u2.y, u3.x, u3.y};
#pragma unroll
        for (int j = 0; j < 8; ++j) {
            const int d = r - RAD - j;
            if (d >= -RAD && d <= RAD) {
                const float wgt = g[d < 0 ? -d : d];
#pragma unroll
                for (int q = 0; q < 8; ++q) acc[j][q] += wgt * u[q];
            }
        }
    }

#pragma unroll
    for (int j = 0; j < 8; ++j) {
        float4 o;
        o.x = pk2(acc[j][0], acc[j][1]);
        o.y = pk2(acc[j][2], acc[j][3]);
        o.z = pk2(acc[j][4], acc[j][5]);
        o.w = pk2(acc[j][6], acc[j][7]);
        *(float4*)(src + (size_t)(p0 + j) * rowdw + cg * 4) = o;
    }
}

// ---------------- kernel 3: 4x4 cubic gather, 2 batches/thread ------------
// grid (1024, 16): thread owns (h,w) for batches b0 and b0+16. Setup,
// weights, offsets and LDS epilogue shared; gathers fully unrolled (ILP).
__global__ __launch_bounds__(256) void k_sample(const float* __restrict__ p01,
                                                const float* __restrict__ p2,
                                                const float2* __restrict__ dxy,
                                                float* __restrict__ out) {
    __shared__ float os[2][768];
    const int t = threadIdx.x;
    const int hw = blockIdx.x * 256 + t;
    const int b0 = blockIdx.y;            // 0..15; pair is b0+16
    const int h = hw >> 10, w = hw & 1023;

    float2 d = dxy[hw];
    float cy = (float)h + d.x;
    float cx = (float)w + d.y;
    float byf = floorf(cy), bxf = floorf(cx);
    int by = (int)byf, bx = (int)bxf;
    float wy[4], wx[4];
    cubw(cy - byf, wy);
    cubw(cx - bxf, wx);

    int iyW[4];
#pragma unroll
    for (int r = 0; r < 4; ++r)
        iyW[r] = min(max(by - 1 + r, 0), H_ - 1) * W_;

    const float* cbA = p01 + (size_t)b0 * HW_;
    const float* cbB = p01 + (size_t)(b0 + 16) * HW_;
    const __half* c2A = (const __half*)p2 + (size_t)b0 * HW_;
    const __half* c2B = (const __half*)p2 + (size_t)(b0 + 16) * HW_;

    float sA0 = 0.f, sA1 = 0.f, sA2 = 0.f;
    float sB0 = 0.f, sB1 = 0.f, sB2 = 0.f;

    if (bx >= 1 && bx <= W_ - 6) {
        // branchless parity-packed weights for the c2 half rows (no arrays)
        const int bx0 = (bx - 1) & ~1;
        const bool par = (bx - 1) & 1;
        const float a_lo = par ? 0.f : wx[0], a_hi = par ? wx[0] : wx[1];
        const float b_lo = par ? wx[1] : wx[2], b_hi = par ? wx[2] : wx[3];
        const float c_lo = par ? wx[3] : 0.f;
        const float wxa = pk2(a_lo, a_hi);
        const float wxb = pk2(b_lo, b_hi);
        const float wxc = pk2(c_lo, 0.f);

#pragma unroll
        for (int r = 0; r < 4; ++r) {
            const int o = iyW[r] + bx - 1;
            const int o2 = iyW[r] + bx0;
            h8a vA = *(const h8a*)(cbA + o);
            h8a vB = *(const h8a*)(cbB + o);
            f4a uA = *(const f4a*)(c2A + o2);
            f4a uB = *(const f4a*)(c2B + o2);
            float tA0 = 0.f, tA1 = 0.f, tB0 = 0.f, tB1 = 0.f;
            tA0 = fmaf((float)vA[0], wx[0], tA0);
            tA1 = fmaf((float)vA[1], wx[0], tA1);
            tB0 = fmaf((float)vB[0], wx[0], tB0);
            tB1 = fmaf((float)vB[1], wx[0], tB1);
            tA0 = fmaf((float)vA[2], wx[1], tA0);
            tA1 = fmaf((float)vA[3], wx[1], tA1);
            tB0 = fmaf((float)vB[2], wx[1], tB0);
            tB1 = fmaf((float)vB[3], wx[1], tB1);
            tA0 = fmaf((float)vA[4], wx[2], tA0);
            tA1 = fmaf((float)vA[5], wx[2], tA1);
            tB0 = fmaf((float)vB[4], wx[2], tB0);
            tB1 = fmaf((float)vB[5], wx[2], tB1);
            tA0 = fmaf((float)vA[6], wx[3], tA0);
            tA1 = fmaf((float)vA[7], wx[3], tA1);
            tB0 = fmaf((float)vB[6], wx[3], tB0);
            tB1 = fmaf((float)vB[7], wx[3], tB1);
            const float wyr = wy[r];
            sA0 = fmaf(wyr, tA0, sA0);
            sA1 = fmaf(wyr, tA1, sA1);
            sB0 = fmaf(wyr, tB0, sB0);
            sB1 = fmaf(wyr, tB1, sB1);
            float dA2 = dot2(uA.z, wxc, dot2(uA.y, wxb, dot2(uA.x, wxa, 0.f)));
            float dB2 = dot2(uB.z, wxc, dot2(uB.y, wxb, dot2(uB.x, wxa, 0.f)));
            sA2 = fmaf(wyr, dA2, sA2);
            sB2 = fmaf(wyr, dB2, sB2);
        }
    } else {
        int ix4[4];
#pragma unroll
        for (int k = 0; k < 4; ++k) ix4[k] = min(max(bx - 1 + k, 0), W_ - 1);
#pragma unroll
        for (int r = 0; r < 4; ++r) {
            float wyr = wy[r];
#pragma unroll
            for (int k = 0; k < 4; ++k) {
                float wk = wyr * wx[k];
                int o = iyW[r] + ix4[k];
                float2 uA = up2(cbA[o]);
                float2 uB = up2(cbB[o]);
                sA0 += wk * uA.x;
                sA1 += wk * uA.y;
                sA2 += wk * __half2float(c2A[o]);
                sB0 += wk * uB.x;
                sB1 += wk * uB.y;
                sB2 += wk * __half2float(c2B[o]);
            }
        }
    }

    os[0][3 * t + 0] = clamp01(sA0);
    os[0][3 * t + 1] = clamp01(sA1);
    os[0][3 * t + 2] = clamp01(sA2);
    os[1][3 * t + 0] = clamp01(sB0);
    os[1][3 * t + 1] = clamp01(sB1);
    os[1][3 * t + 2] = clamp01(sB2);
    __syncthreads();

    if (t < 192) {
        float4 vA = *(const float4*)(&os[0][0] + 4 * t);
        float4 vB = *(const float4*)(&os[1][0] + 4 * t);
        float* oA = out + ((size_t)b0 * HW_ + (size_t)blockIdx.x * 256) * 3;
        float* oB = out + ((size_t)(b0 + 16) * HW_ + (size_t)blockIdx.x * 256) * 3;
        *(float4*)(oA + 4 * t) = vA;
        *(float4*)(oB + 4 * t) = vB;
    }
}

extern "C" void kernel_launch(void* const* d_in, const int* in_sizes, int n_in,
                              void* d_out, int out_size, void* d_ws, size_t ws_size,
                              hipStream_t stream) {
    const float* x = (const float*)d_in[0];      // [32,256,1024,3]
    const float* disp = (const float*)d_in[1];   // [2,3,3]
    float* out = (float*)d_out;

    char* ws = (char*)d_ws;
    float* p01 = (float*)ws;                       // 32 MiB (half2 per pixel)
    float* p2 = (float*)(ws + 33554432ull);        // 16 MiB (half c2)
    float2* dxy = (float2*)(ws + 50331648ull);     // 2 MiB

    k_disp<<<dim3(HW_ / 256), dim3(256), 0, stream>>>(disp, dxy);

    k_wfilt<<<dim3(B_ * H_), dim3(256), 0, stream>>>(x, p01, p2);

    k_hfilt<<<dim3(32, 48), dim3(256), 0, stream>>>(p01, p2);

    k_sample<<<dim3(HW_ / 256, B_ / 2), dim3(256), 0, stream>>>(p01, p2, dxy, out);
}

// Round 13
// 113.015 us; speedup vs baseline: 1.2619x; 1.0004x over previous
//
#include <hip/hip_runtime.h>
#include <hip/hip_fp16.h>
#include <math.h>

// Elastic transform: [32,256,1024,3] fp32, 3x3 control grid displacement.
//   k_disp   : dense (dy,dx) float2 field [256,1024] from 3x3 control points
//   k_wfilt  : spline prefilter along W (17-tap mirror FIR, f32 math), x ->
//              p01 (half2 per pixel: c0,c1) + p2 (half per pixel: c2)
//   k_hfilt  : prefilter along H in place, f32 math, uniform half-pair FIR
//   k_sample : 4x4 cubic gather, one thread per (h,w) x FOUR batches
//              (b0,b0+8,b0+16,b0+24): setup/weights/offsets/LDS-epilogue
//              amortized 4-way; c0/c1 taps via v_fma_mix, c2 via fdot2.
//
// fp16 is STORAGE ONLY except fdot2 (fp16 multiply, f32 accumulate).

#define H_ 256
#define W_ 1024
#define B_ 32
#define RAD 8                // |z|^9 trunc err ~1e-4 << 2e-2 threshold
#define ROWF 3072            // W_*3 floats per (b,h) row of x
#define HW_ (H_ * W_)        // 262144 pixels per plane
#define HW2 (HW_ / 2)        // dwords per fp16 single-channel plane
#define W2 (W_ / 2)          // dwords per fp16 single-channel row

typedef float f4a __attribute__((ext_vector_type(4), aligned(4)));
typedef float f3a __attribute__((ext_vector_type(3), aligned(4)));
typedef _Float16 h2 __attribute__((ext_vector_type(2)));
typedef _Float16 h8a __attribute__((ext_vector_type(8), aligned(4)));

#if defined(__has_builtin)
#if __has_builtin(__builtin_amdgcn_fdot2)
#define HAVE_FDOT2 1
#endif
#endif

__device__ __forceinline__ float dot2(float dword, float wgt_dword, float c) {
    h2 a = __builtin_bit_cast(h2, dword);
    h2 b = __builtin_bit_cast(h2, wgt_dword);
#ifdef HAVE_FDOT2
    return __builtin_amdgcn_fdot2(a, b, c, false);
#else
    return (float)a.x * (float)b.x + (float)a.y * (float)b.y + c;
#endif
}

__device__ __forceinline__ float b3f(float t) {
    float a = fabsf(t);
    if (a < 1.0f) return (4.0f - 6.0f * a * a + 3.0f * a * a * a) * (1.0f / 6.0f);
    if (a < 2.0f) { float s = 2.0f - a; return s * s * s * (1.0f / 6.0f); }
    return 0.0f;
}

__device__ __forceinline__ void cubw(float f, float* w) {
    float f2 = f * f, f3 = f2 * f;
    float om = 1.0f - f;
    w[0] = om * om * om * (1.0f / 6.0f);
    w[1] = (3.0f * f3 - 6.0f * f2 + 4.0f) * (1.0f / 6.0f);
    w[2] = (-3.0f * f3 + 3.0f * f2 + 3.0f * f + 1.0f) * (1.0f / 6.0f);
    w[3] = f3 * (1.0f / 6.0f);
}

__device__ __forceinline__ float clamp01(float v) {
    return fminf(fmaxf(v, 0.0f), 1.0f);
}

__device__ __forceinline__ float2 up2(float d) {
    return __half22float2(__builtin_bit_cast(__half2, d));
}
__device__ __forceinline__ float pk2(float a, float b) {
    return __builtin_bit_cast(float, __floats2half2_rn(a, b));
}

__device__ __forceinline__ void basis3(int i, int n, float& w0, float& w1, float& w2) {
    float u = (float)i * 2.0f / (float)(n - 1);
    int base = (int)floorf(u);
    w0 = w1 = w2 = 0.0f;
#pragma unroll
    for (int k = -1; k < 3; ++k) {
        int id = base + k;
        float bw = b3f(u - (float)id);
        int j = id < 0 ? -id : id;
        j &= 3;
        if (j == 3) j = 1;
        if (j == 0) w0 += bw; else if (j == 1) w1 += bw; else w2 += bw;
    }
}

// ---------------- kernel 0: displacement field (dy,dx) --------------------
__global__ __launch_bounds__(256) void k_disp(const float* __restrict__ disp,
                                              float2* __restrict__ dxy) {
    int idx = blockIdx.x * 256 + threadIdx.x;
    int h = idx >> 10, w = idx & 1023;

    const float A[3][3] = {{1.75f, -1.0f, 0.25f},
                           {-0.5f,  2.0f, -0.5f},
                           {0.25f, -1.0f, 1.75f}};
    float Ty[3][3], Tx[3][3];
#pragma unroll
    for (int i = 0; i < 3; ++i)
#pragma unroll
        for (int j = 0; j < 3; ++j) {
            float ty = 0.f, tx = 0.f;
#pragma unroll
            for (int k = 0; k < 3; ++k) {
                ty += A[i][k] * (5.0f * disp[k * 3 + j]);
                tx += A[i][k] * (5.0f * disp[9 + k * 3 + j]);
            }
            Ty[i][j] = ty; Tx[i][j] = tx;
        }
    float Cy[3][3], Cx[3][3];
#pragma unroll
    for (int i = 0; i < 3; ++i)
#pragma unroll
        for (int j = 0; j < 3; ++j) {
            float ty = 0.f, tx = 0.f;
#pragma unroll
            for (int k = 0; k < 3; ++k) {
                ty += Ty[i][k] * A[j][k];
                tx += Tx[i][k] * A[j][k];
            }
            Cy[i][j] = ty; Cx[i][j] = tx;
        }

    float rh0, rh1, rh2, rw0, rw1, rw2;
    basis3(h, H_, rh0, rh1, rh2);
    basis3(w, W_, rw0, rw1, rw2);
    float rh[3] = {rh0, rh1, rh2}, rw[3] = {rw0, rw1, rw2};

    float dy = 0.f, dx = 0.f;
#pragma unroll
    for (int i = 0; i < 3; ++i)
#pragma unroll
        for (int j = 0; j < 3; ++j) {
            dy += rh[i] * Cy[i][j] * rw[j];
            dx += rh[i] * Cx[i][j] * rw[j];
        }
    dxy[idx] = make_float2(dy, dx);
}

// ---------------- kernel 1: prefilter along W (f32 math) ------------------
// per channel LDS: [8 halo][1024][8 halo] = 1040, stride 1040
#define PLN 1040
__global__ __launch_bounds__(256) void k_wfilt(const float* __restrict__ x,
                                               float* __restrict__ p01,  // half2/px
                                               float* __restrict__ p2) { // half/px
    __shared__ float pl[3 * PLN];        // 12480 B
    const int bp = blockIdx.x;           // b*256 + h
    const int t = threadIdx.x;
    const float* row = x + (size_t)bp * ROWF;

    {
        float4 v0 = *(const float4*)(row + 12 * t);
        float4 v1 = *(const float4*)(row + 12 * t + 4);
        float4 v2 = *(const float4*)(row + 12 * t + 8);
        float4 c0, c1, c2;
        c0.x = v0.x; c0.y = v0.w; c0.z = v1.z; c0.w = v2.y;
        c1.x = v0.y; c1.y = v1.x; c1.z = v1.w; c1.w = v2.z;
        c2.x = v0.z; c2.y = v1.y; c2.z = v2.x; c2.w = v2.w;
        *(float4*)(pl + 0 * PLN + 8 + 4 * t) = c0;
        *(float4*)(pl + 1 * PLN + 8 + 4 * t) = c1;
        *(float4*)(pl + 2 * PLN + 8 + 4 * t) = c2;
    }
    __syncthreads();

    if (t < 48) {                        // mirror halos: 3ch x (8 left + 8 right)
        int c = t >> 4, i = t & 15;
        float* p = pl + c * PLN;
        if (i < 8) { int j = i + 1; p[8 - j] = p[8 + j]; }
        else { int r = i - 8; p[1032 + r] = p[1030 - r]; }
    }
    __syncthreads();

    float g[RAD + 1];
    g[0] = 1.7320508075688773f;
#pragma unroll
    for (int k = 1; k <= RAD; ++k) g[k] = g[k - 1] * (-0.26794919243112270647f);

    float res[3][4];
#pragma unroll
    for (int c = 0; c < 3; ++c) {
        const float* p = pl + c * PLN + 4 * t;
        float w[20];
#pragma unroll
        for (int i = 0; i < 5; ++i) {
            float4 v = *(const float4*)(p + 4 * i);
            w[4 * i] = v.x; w[4 * i + 1] = v.y; w[4 * i + 2] = v.z; w[4 * i + 3] = v.w;
        }
#pragma unroll
        for (int j = 0; j < 4; ++j) {
            float a = g[0] * w[j + 8];
#pragma unroll
            for (int k = 1; k <= 8; ++k)
                a += g[k] * (w[j + 8 - k] + w[j + 8 + k]);
            res[c][j] = a;
        }
    }

    const int b = bp >> 8, h = bp & 255;
    float4 o01;
    o01.x = pk2(res[0][0], res[1][0]);
    o01.y = pk2(res[0][1], res[1][1]);
    o01.z = pk2(res[0][2], res[1][2]);
    o01.w = pk2(res[0][3], res[1][3]);
    *(float4*)(p01 + (size_t)b * HW_ + (size_t)h * W_ + 4 * t) = o01;
    float2 o2;
    o2.x = pk2(res[2][0], res[2][1]);
    o2.y = pk2(res[2][2], res[2][3]);
    *(float2*)(p2 + (size_t)b * HW2 + (size_t)h * W2 + 2 * t) = o2;
}

// ---------------- kernel 2: prefilter along H, in place, uniform ----------
// grid (32, 48): p01 planes (32 rows-of-grid) + p2 planes (16, paired).
#define TSTR 40
__global__ __launch_bounds__(256) void k_hfilt(float* __restrict__ p01,
                                               float* __restrict__ p2) {
    __shared__ float tile[H_ * TSTR];   // 40 KiB
    const int t = threadIdx.x;
    const int gy = blockIdx.y;
    float* src;
    int rowdw;
    if (gy < 32) {
        src = p01 + (size_t)gy * HW_ + blockIdx.x * 32;
        rowdw = W_;
    } else {
        int p2i = ((gy - 32) << 1) | (blockIdx.x >> 4);
        src = p2 + (size_t)p2i * HW2 + (blockIdx.x & 15) * 32;
        rowdw = W2;
    }

#pragma unroll
    for (int it = 0; it < 8; ++it) {
        int idx = t + it * 256;          // 0..2047 float4s
        int r = idx >> 3, seg = idx & 7;
        *(float4*)(tile + r * TSTR + seg * 4) =
            *(const float4*)(src + (size_t)r * rowdw + seg * 4);
    }
    __syncthreads();

    float g[RAD + 1];
    g[0] = 1.7320508075688773f;
#pragma unroll
    for (int k = 1; k <= RAD; ++k) g[k] = g[k - 1] * (-0.26794919243112270647f);

    const int cg = t & 7;          // dword4 column group (8 halves)
    const int prow = t >> 3;       // 0..31
    const int p0 = prow * 8;

    float acc[8][8];
#pragma unroll
    for (int j = 0; j < 8; ++j)
#pragma unroll
        for (int q = 0; q < 8; ++q) acc[j][q] = 0.f;

#pragma unroll
    for (int r = 0; r < 8 + 2 * RAD; ++r) {    // 24 rows
        int hh = p0 - RAD + r;
        int m1 = hh < 0 ? -hh : hh;
        int m2 = 2 * (H_ - 1) - hh;
        int mp = m1 < m2 ? m1 : m2;
        float4 v = *(const float4*)(tile + mp * TSTR + cg * 4);
        float2 u0 = up2(v.x), u1 = up2(v.y), u2 = up2(v.z), u3 = up2(v.w);
        float u[8] = {u0.x, u0.y, u1.x, u1.y, u2.x, u2.y, u3.x, u3.y};
#pragma unroll
        for (int j = 0; j < 8; ++j) {
            const int d = r - RAD - j;
            if (d >= -RAD && d <= RAD) {
                const float wgt = g[d < 0 ? -d : d];
#pragma unroll
                for (int q = 0; q < 8; ++q) acc[j][q] += wgt * u[q];
            }
        }
    }

#pragma unroll
    for (int j = 0; j < 8; ++j) {
        float4 o;
        o.x = pk2(acc[j][0], acc[j][1]);
        o.y = pk2(acc[j][2], acc[j][3]);
        o.z = pk2(acc[j][4], acc[j][5]);
        o.w = pk2(acc[j][6], acc[j][7]);
        *(float4*)(src + (size_t)(p0 + j) * rowdw + cg * 4) = o;
    }
}

// ---------------- kernel 3: 4x4 cubic gather, 4 batches/thread ------------
// grid (1024, 8): thread owns (h,w) for batches b0,b0+8,b0+16,b0+24.
// Setup, weights, offsets, LDS epilogue amortized 4-way; rows unrolled (ILP).
__global__ __launch_bounds__(256) void k_sample(const float* __restrict__ p01,
                                                const float* __restrict__ p2,
                                                const float2* __restrict__ dxy,
                                                float* __restrict__ out) {
    __shared__ float os[4][768];
    const int t = threadIdx.x;
    const int hw = blockIdx.x * 256 + t;
    const int b0 = blockIdx.y;            // 0..7; batches b0+8u
    const int h = hw >> 10, w = hw & 1023;

    float2 d = dxy[hw];
    float cy = (float)h + d.x;
    float cx = (float)w + d.y;
    float byf = floorf(cy), bxf = floorf(cx);
    int by = (int)byf, bx = (int)bxf;
    float wy[4], wx[4];
    cubw(cy - byf, wy);
    cubw(cx - bxf, wx);

    int iyW[4];
#pragma unroll
    for (int r = 0; r < 4; ++r)
        iyW[r] = min(max(by - 1 + r, 0), H_ - 1) * W_;

    const float* cb[4];
    const __half* c2[4];
#pragma unroll
    for (int u = 0; u < 4; ++u) {
        cb[u] = p01 + (size_t)(b0 + 8 * u) * HW_;
        c2[u] = (const __half*)p2 + (size_t)(b0 + 8 * u) * HW_;
    }

    float s[4][3];
#pragma unroll
    for (int u = 0; u < 4; ++u) { s[u][0] = 0.f; s[u][1] = 0.f; s[u][2] = 0.f; }

    if (bx >= 1 && bx <= W_ - 6) {
        // branchless parity-packed weights for the c2 half rows
        const int bx0 = (bx - 1) & ~1;
        const bool par = (bx - 1) & 1;
        const float a_lo = par ? 0.f : wx[0], a_hi = par ? wx[0] : wx[1];
        const float b_lo = par ? wx[1] : wx[2], b_hi = par ? wx[2] : wx[3];
        const float c_lo = par ? wx[3] : 0.f;
        const float wxa = pk2(a_lo, a_hi);
        const float wxb = pk2(b_lo, b_hi);
        const float wxc = pk2(c_lo, 0.f);

#pragma unroll
        for (int r = 0; r < 4; ++r) {
            const int o = iyW[r] + bx - 1;
            const int o2 = iyW[r] + bx0;
            const float wyr = wy[r];
            h8a v[4];
            f3a u2[4];
#pragma unroll
            for (int u = 0; u < 4; ++u) {
                v[u] = *(const h8a*)(cb[u] + o);
                u2[u] = *(const f3a*)(c2[u] + o2);
            }
#pragma unroll
            for (int u = 0; u < 4; ++u) {
                float t0 = fmaf((float)v[u][0], wx[0], 0.f);
                float t1 = fmaf((float)v[u][1], wx[0], 0.f);
                t0 = fmaf((float)v[u][2], wx[1], t0);
                t1 = fmaf((float)v[u][3], wx[1], t1);
                t0 = fmaf((float)v[u][4], wx[2], t0);
                t1 = fmaf((float)v[u][5], wx[2], t1);
                t0 = fmaf((float)v[u][6], wx[3], t0);
                t1 = fmaf((float)v[u][7], wx[3], t1);
                s[u][0] = fmaf(wyr, t0, s[u][0]);
                s[u][1] = fmaf(wyr, t1, s[u][1]);
                float d2 = dot2(u2[u].z, wxc, dot2(u2[u].y, wxb, dot2(u2[u].x, wxa, 0.f)));
                s[u][2] = fmaf(wyr, d2, s[u][2]);
            }
        }
    } else {
        int ix4[4];
#pragma unroll
        for (int k = 0; k < 4; ++k) ix4[k] = min(max(bx - 1 + k, 0), W_ - 1);
#pragma unroll
        for (int r = 0; r < 4; ++r) {
            float wyr = wy[r];
#pragma unroll
            for (int k = 0; k < 4; ++k) {
                float wk = wyr * wx[k];
                int o = iyW[r] + ix4[k];
#pragma unroll
                for (int u = 0; u < 4; ++u) {
                    float2 uv = up2(cb[u][o]);
                    s[u][0] += wk * uv.x;
                    s[u][1] += wk * uv.y;
                    s[u][2] += wk * __half2float(c2[u][o]);
                }
            }
        }
    }

#pragma unroll
    for (int u = 0; u < 4; ++u) {
        os[u][3 * t + 0] = clamp01(s[u][0]);
        os[u][3 * t + 1] = clamp01(s[u][1]);
        os[u][3 * t + 2] = clamp01(s[u][2]);
    }
    __syncthreads();

    if (t < 192) {
#pragma unroll
        for (int u = 0; u < 4; ++u) {
            float4 v = *(const float4*)(&os[u][0] + 4 * t);
            float* o = out + ((size_t)(b0 + 8 * u) * HW_ + (size_t)blockIdx.x * 256) * 3;
            *(float4*)(o + 4 * t) = v;
        }
    }
}

extern "C" void kernel_launch(void* const* d_in, const int* in_sizes, int n_in,
                              void* d_out, int out_size, void* d_ws, size_t ws_size,
                              hipStream_t stream) {
    const float* x = (const float*)d_in[0];      // [32,256,1024,3]
    const float* disp = (const float*)d_in[1];   // [2,3,3]
    float* out = (float*)d_out;

    char* ws = (char*)d_ws;
    float* p01 = (float*)ws;                       // 32 MiB (half2 per pixel)
    float* p2 = (float*)(ws + 33554432ull);        // 16 MiB (half c2)
    float2* dxy = (float2*)(ws + 50331648ull);     // 2 MiB

    k_disp<<<dim3(HW_ / 256), dim3(256), 0, stream>>>(disp, dxy);

    k_wfilt<<<dim3(B_ * H_), dim3(256), 0, stream>>>(x, p01, p2);

    k_hfilt<<<dim3(32, 48), dim3(256), 0, stream>>>(p01, p2);

    k_sample<<<dim3(HW_ / 256, B_ / 4), dim3(256), 0, stream>>>(p01, p2, dxy, out);
}

// Round 14
// 101.189 us; speedup vs baseline: 1.4094x; 1.1169x over previous
//
#include <hip/hip_runtime.h>
#include <hip/hip_fp16.h>
#include <math.h>

// Elastic transform: [32,256,1024,3] fp32, 3x3 control grid displacement.
//   k_disp   : dense (dy,dx) float2 field [256,1024] from 3x3 control points
//   k_wfilt  : spline prefilter along W (17-tap mirror FIR, f32 math), x ->
//              48 PAIR-PLANES: dword = fp16 pair (batch p, batch p+16),
//              planes indexed [pair p (16)][channel (3)][h][w]
//   k_hfilt  : prefilter along H in place, f32 math, uniform over 48 planes
//   k_sample : 4x4 cubic gather; one thread -> (h,w) x batch-pair (b, b+16);
//              3 dwordx4 tap loads/row serve BOTH batches (6 loads/output);
//              x-reduction in v_pk_fma_f16 (bounded |c|<=3.4), y in f32
//
// fp16 storage; pk-f16 math ONLY in k_sample's x-reduction (f32 y-combine).

#define H_ 256
#define W_ 1024
#define B_ 32
#define RAD 8                // |z|^9 trunc err ~1e-4 << 2e-2 threshold
#define ROWF 3072            // W_*3 floats per (b,h) row of x
#define HW_ (H_ * W_)        // 262144 dwords per pair-plane

typedef float f4a __attribute__((ext_vector_type(4), aligned(4)));
typedef _Float16 h2 __attribute__((ext_vector_type(2)));

__device__ __forceinline__ h2 bch2(float d) { return __builtin_bit_cast(h2, d); }

__device__ __forceinline__ float b3f(float t) {
    float a = fabsf(t);
    if (a < 1.0f) return (4.0f - 6.0f * a * a + 3.0f * a * a * a) * (1.0f / 6.0f);
    if (a < 2.0f) { float s = 2.0f - a; return s * s * s * (1.0f / 6.0f); }
    return 0.0f;
}

__device__ __forceinline__ void cubw(float f, float* w) {
    float f2 = f * f, f3 = f2 * f;
    float om = 1.0f - f;
    w[0] = om * om * om * (1.0f / 6.0f);
    w[1] = (3.0f * f3 - 6.0f * f2 + 4.0f) * (1.0f / 6.0f);
    w[2] = (-3.0f * f3 + 3.0f * f2 + 3.0f * f + 1.0f) * (1.0f / 6.0f);
    w[3] = f3 * (1.0f / 6.0f);
}

__device__ __forceinline__ float clamp01(float v) {
    return fminf(fmaxf(v, 0.0f), 1.0f);
}

__device__ __forceinline__ float2 up2(float d) {
    return __half22float2(__builtin_bit_cast(__half2, d));
}
__device__ __forceinline__ float pk2(float a, float b) {
    return __builtin_bit_cast(float, __floats2half2_rn(a, b));
}

__device__ __forceinline__ void basis3(int i, int n, float& w0, float& w1, float& w2) {
    float u = (float)i * 2.0f / (float)(n - 1);
    int base = (int)floorf(u);
    w0 = w1 = w2 = 0.0f;
#pragma unroll
    for (int k = -1; k < 3; ++k) {
        int id = base + k;
        float bw = b3f(u - (float)id);
        int j = id < 0 ? -id : id;
        j &= 3;
        if (j == 3) j = 1;
        if (j == 0) w0 += bw; else if (j == 1) w1 += bw; else w2 += bw;
    }
}

// ---------------- kernel 0: displacement field (dy,dx) --------------------
__global__ __launch_bounds__(256) void k_disp(const float* __restrict__ disp,
                                              float2* __restrict__ dxy) {
    int idx = blockIdx.x * 256 + threadIdx.x;
    int h = idx >> 10, w = idx & 1023;

    const float A[3][3] = {{1.75f, -1.0f, 0.25f},
                           {-0.5f,  2.0f, -0.5f},
                           {0.25f, -1.0f, 1.75f}};
    float Ty[3][3], Tx[3][3];
#pragma unroll
    for (int i = 0; i < 3; ++i)
#pragma unroll
        for (int j = 0; j < 3; ++j) {
            float ty = 0.f, tx = 0.f;
#pragma unroll
            for (int k = 0; k < 3; ++k) {
                ty += A[i][k] * (5.0f * disp[k * 3 + j]);
                tx += A[i][k] * (5.0f * disp[9 + k * 3 + j]);
            }
            Ty[i][j] = ty; Tx[i][j] = tx;
        }
    float Cy[3][3], Cx[3][3];
#pragma unroll
    for (int i = 0; i < 3; ++i)
#pragma unroll
        for (int j = 0; j < 3; ++j) {
            float ty = 0.f, tx = 0.f;
#pragma unroll
            for (int k = 0; k < 3; ++k) {
                ty += Ty[i][k] * A[j][k];
                tx += Tx[i][k] * A[j][k];
            }
            Cy[i][j] = ty; Cx[i][j] = tx;
        }

    float rh0, rh1, rh2, rw0, rw1, rw2;
    basis3(h, H_, rh0, rh1, rh2);
    basis3(w, W_, rw0, rw1, rw2);
    float rh[3] = {rh0, rh1, rh2}, rw[3] = {rw0, rw1, rw2};

    float dy = 0.f, dx = 0.f;
#pragma unroll
    for (int i = 0; i < 3; ++i)
#pragma unroll
        for (int j = 0; j < 3; ++j) {
            dy += rh[i] * Cy[i][j] * rw[j];
            dx += rh[i] * Cx[i][j] * rw[j];
        }
    dxy[idx] = make_float2(dy, dx);
}

// ---------------- kernel 1: prefilter along W -> pair-planes --------------
// block bp = p*256 + h handles rows (p,h) AND (p+16,h); per channel LDS row:
// [8 halo][1024][8 halo] = 1040; 6 rows (2 batches x 3 ch) = 25 KB.
#define PLN 1040
__global__ __launch_bounds__(256) void k_wfilt(const float* __restrict__ x,
                                               float* __restrict__ pairP) {
    __shared__ float pl[6 * PLN];
    const int bp = blockIdx.x;           // p*256 + h, p in 0..15
    const int p = bp >> 8, h = bp & 255;
    const int t = threadIdx.x;

#pragma unroll
    for (int bi = 0; bi < 2; ++bi) {
        const float* row = x + ((size_t)(p + 16 * bi) * H_ + h) * ROWF;
        float4 v0 = *(const float4*)(row + 12 * t);
        float4 v1 = *(const float4*)(row + 12 * t + 4);
        float4 v2 = *(const float4*)(row + 12 * t + 8);
        float4 c0, c1, c2;
        c0.x = v0.x; c0.y = v0.w; c0.z = v1.z; c0.w = v2.y;
        c1.x = v0.y; c1.y = v1.x; c1.z = v1.w; c1.w = v2.z;
        c2.x = v0.z; c2.y = v1.y; c2.z = v2.x; c2.w = v2.w;
        *(float4*)(pl + (bi * 3 + 0) * PLN + 8 + 4 * t) = c0;
        *(float4*)(pl + (bi * 3 + 1) * PLN + 8 + 4 * t) = c1;
        *(float4*)(pl + (bi * 3 + 2) * PLN + 8 + 4 * t) = c2;
    }
    __syncthreads();

    if (t < 96) {                        // mirror halos: 6 rows x (8+8)
        int rb = t / 48, rem = t % 48;
        int c = rem >> 4, i = rem & 15;
        float* pp = pl + (rb * 3 + c) * PLN;
        if (i < 8) { int j = i + 1; pp[8 - j] = pp[8 + j]; }
        else { int r = i - 8; pp[1032 + r] = pp[1030 - r]; }
    }
    __syncthreads();

    float g[RAD + 1];
    g[0] = 1.7320508075688773f;
#pragma unroll
    for (int k = 1; k <= RAD; ++k) g[k] = g[k - 1] * (-0.26794919243112270647f);

    float res[2][3][4];
#pragma unroll
    for (int bi = 0; bi < 2; ++bi)
#pragma unroll
        for (int c = 0; c < 3; ++c) {
            const float* pp = pl + (bi * 3 + c) * PLN + 4 * t;
            float w[20];
#pragma unroll
            for (int i = 0; i < 5; ++i) {
                float4 v = *(const float4*)(pp + 4 * i);
                w[4 * i] = v.x; w[4 * i + 1] = v.y;
                w[4 * i + 2] = v.z; w[4 * i + 3] = v.w;
            }
#pragma unroll
            for (int j = 0; j < 4; ++j) {
                float a = g[0] * w[j + 8];
#pragma unroll
                for (int k = 1; k <= 8; ++k)
                    a += g[k] * (w[j + 8 - k] + w[j + 8 + k]);
                res[bi][c][j] = a;
            }
        }

#pragma unroll
    for (int c = 0; c < 3; ++c) {
        float4 o;
        o.x = pk2(res[0][c][0], res[1][c][0]);
        o.y = pk2(res[0][c][1], res[1][c][1]);
        o.z = pk2(res[0][c][2], res[1][c][2]);
        o.w = pk2(res[0][c][3], res[1][c][3]);
        *(float4*)(pairP + (size_t)(p * 3 + c) * HW_ + (size_t)h * W_ + 4 * t) = o;
    }
}

// ---------------- kernel 2: prefilter along H, in place, uniform ----------
// grid (32, 48): 48 identical pair-planes, 32-dword chunks, rows = W_ dwords.
#define TSTR 40
__global__ __launch_bounds__(256) void k_hfilt(float* __restrict__ pairP) {
    __shared__ float tile[H_ * TSTR];   // 40 KiB
    const int t = threadIdx.x;
    float* src = pairP + (size_t)blockIdx.y * HW_ + blockIdx.x * 32;

#pragma unroll
    for (int it = 0; it < 8; ++it) {
        int idx = t + it * 256;          // 0..2047 float4s
        int r = idx >> 3, seg = idx & 7;
        *(float4*)(tile + r * TSTR + seg * 4) =
            *(const float4*)(src + (size_t)r * W_ + seg * 4);
    }
    __syncthreads();

    float g[RAD + 1];
    g[0] = 1.7320508075688773f;
#pragma unroll
    for (int k = 1; k <= RAD; ++k) g[k] = g[k - 1] * (-0.26794919243112270647f);

    const int cg = t & 7;          // dword4 column group (8 halves)
    const int prow = t >> 3;       // 0..31
    const int p0 = prow * 8;

    float acc[8][8];
#pragma unroll
    for (int j = 0; j < 8; ++j)
#pragma unroll
        for (int q = 0; q < 8; ++q) acc[j][q] = 0.f;

#pragma unroll
    for (int r = 0; r < 8 + 2 * RAD; ++r) {    // 24 rows
        int hh = p0 - RAD + r;
        int m1 = hh < 0 ? -hh : hh;
        int m2 = 2 * (H_ - 1) - hh;
        int mp = m1 < m2 ? m1 : m2;
        float4 v = *(const float4*)(tile + mp * TSTR + cg * 4);
        float2 u0 = up2(v.x), u1 = up2(v.y), u2 = up2(v.z), u3 = up2(v.w);
        float u[8] = {u0.x, u0.y, u1.x, u1.y, u2.x, u2.y, u3.x, u3.y};
#pragma unroll
        for (int j = 0; j < 8; ++j) {
            const int d = r - RAD - j;
            if (d >= -RAD && d <= RAD) {
                const float wgt = g[d < 0 ? -d : d];
#pragma unroll
                for (int q = 0; q < 8; ++q) acc[j][q] += wgt * u[q];
            }
        }
    }

#pragma unroll
    for (int j = 0; j < 8; ++j) {
        float4 o;
        o.x = pk2(acc[j][0], acc[j][1]);
        o.y = pk2(acc[j][2], acc[j][3]);
        o.z = pk2(acc[j][4], acc[j][5]);
        o.w = pk2(acc[j][6], acc[j][7]);
        *(float4*)(src + (size_t)(p0 + j) * W_ + cg * 4) = o;
    }
}

// ---------------- kernel 3: 4x4 cubic gather, batch-pair/thread -----------
// grid (1024, 16): thread owns (h,w) for batches (b0, b0+16). Each tap row:
// 3 unaligned dwordx4 loads serve both batches & all channels.
__global__ __launch_bounds__(256) void k_sample(const float* __restrict__ pairP,
                                                const float2* __restrict__ dxy,
                                                float* __restrict__ out) {
    __shared__ float os[2][768];
    const int t = threadIdx.x;
    const int hw = blockIdx.x * 256 + t;
    const int b0 = blockIdx.y;            // 0..15; pair (b0, b0+16)
    const int h = hw >> 10, w = hw & 1023;

    float2 d = dxy[hw];
    float cy = (float)h + d.x;
    float cx = (float)w + d.y;
    float byf = floorf(cy), bxf = floorf(cx);
    int by = (int)byf, bx = (int)bxf;
    float wy[4], wx[4];
    cubw(cy - byf, wy);
    cubw(cx - bxf, wx);

    int iyW[4];
#pragma unroll
    for (int r = 0; r < 4; ++r)
        iyW[r] = min(max(by - 1 + r, 0), H_ - 1) * W_;

    const float* pc0 = pairP + (size_t)(b0 * 3) * HW_;
    const float* pc1 = pc0 + HW_;
    const float* pc2 = pc1 + HW_;

    float sA0 = 0.f, sA1 = 0.f, sA2 = 0.f;
    float sB0 = 0.f, sB1 = 0.f, sB2 = 0.f;

    if (bx >= 1 && bx <= W_ - 3) {
        const h2 w0 = bch2(pk2(wx[0], wx[0]));
        const h2 w1 = bch2(pk2(wx[1], wx[1]));
        const h2 w2 = bch2(pk2(wx[2], wx[2]));
        const h2 w3 = bch2(pk2(wx[3], wx[3]));

#pragma unroll
        for (int r = 0; r < 4; ++r) {
            const int o = iyW[r] + bx - 1;
            f4a v0 = *(const f4a*)(pc0 + o);
            f4a v1 = *(const f4a*)(pc1 + o);
            f4a v2 = *(const f4a*)(pc2 + o);
            const float wyr = wy[r];
            // x-reduction in packed f16 (both batches per lane-pair)
            h2 a0 = bch2(v0.x) * w0 + bch2(v0.y) * w1;
            a0 = a0 + bch2(v0.z) * w2 + bch2(v0.w) * w3;
            h2 a1 = bch2(v1.x) * w0 + bch2(v1.y) * w1;
            a1 = a1 + bch2(v1.z) * w2 + bch2(v1.w) * w3;
            h2 a2 = bch2(v2.x) * w0 + bch2(v2.y) * w1;
            a2 = a2 + bch2(v2.z) * w2 + bch2(v2.w) * w3;
            // y-combine in f32
            float2 u0 = up2(__builtin_bit_cast(float, a0));
            float2 u1 = up2(__builtin_bit_cast(float, a1));
            float2 u2 = up2(__builtin_bit_cast(float, a2));
            sA0 = fmaf(wyr, u0.x, sA0); sB0 = fmaf(wyr, u0.y, sB0);
            sA1 = fmaf(wyr, u1.x, sA1); sB1 = fmaf(wyr, u1.y, sB1);
            sA2 = fmaf(wyr, u2.x, sA2); sB2 = fmaf(wyr, u2.y, sB2);
        }
    } else {
        int ix4[4];
#pragma unroll
        for (int k = 0; k < 4; ++k) ix4[k] = min(max(bx - 1 + k, 0), W_ - 1);
#pragma unroll
        for (int r = 0; r < 4; ++r) {
            float wyr = wy[r];
#pragma unroll
            for (int k = 0; k < 4; ++k) {
                float wk = wyr * wx[k];
                int o = iyW[r] + ix4[k];
                float2 u0 = up2(pc0[o]);
                float2 u1 = up2(pc1[o]);
                float2 u2 = up2(pc2[o]);
                sA0 += wk * u0.x; sB0 += wk * u0.y;
                sA1 += wk * u1.x; sB1 += wk * u1.y;
                sA2 += wk * u2.x; sB2 += wk * u2.y;
            }
        }
    }

    os[0][3 * t + 0] = clamp01(sA0);
    os[0][3 * t + 1] = clamp01(sA1);
    os[0][3 * t + 2] = clamp01(sA2);
    os[1][3 * t + 0] = clamp01(sB0);
    os[1][3 * t + 1] = clamp01(sB1);
    os[1][3 * t + 2] = clamp01(sB2);
    __syncthreads();

    if (t < 192) {
        float4 vA = *(const float4*)(&os[0][0] + 4 * t);
        float4 vB = *(const float4*)(&os[1][0] + 4 * t);
        float* oA = out + ((size_t)b0 * HW_ + (size_t)blockIdx.x * 256) * 3;
        float* oB = out + ((size_t)(b0 + 16) * HW_ + (size_t)blockIdx.x * 256) * 3;
        *(float4*)(oA + 4 * t) = vA;
        *(float4*)(oB + 4 * t) = vB;
    }
}

extern "C" void kernel_launch(void* const* d_in, const int* in_sizes, int n_in,
                              void* d_out, int out_size, void* d_ws, size_t ws_size,
                              hipStream_t stream) {
    const float* x = (const float*)d_in[0];      // [32,256,1024,3]
    const float* disp = (const float*)d_in[1];   // [2,3,3]
    float* out = (float*)d_out;

    char* ws = (char*)d_ws;
    float* pairP = (float*)ws;                     // 48 MiB: 48 pair-planes
    float2* dxy = (float2*)(ws + 50331648ull);     // 2 MiB

    k_disp<<<dim3(HW_ / 256), dim3(256), 0, stream>>>(disp, dxy);

    k_wfilt<<<dim3((B_ / 2) * H_), dim3(256), 0, stream>>>(x, pairP);

    k_hfilt<<<dim3(32, 48), dim3(256), 0, stream>>>(pairP);

    k_sample<<<dim3(HW_ / 256, B_ / 2), dim3(256), 0, stream>>>(pairP, dxy, out);
}

// Round 15
// 96.407 us; speedup vs baseline: 1.4793x; 1.0496x over previous
//
#include <hip/hip_runtime.h>
#include <hip/hip_fp16.h>
#include <math.h>

// Elastic transform: [32,256,1024,3] fp32, 3x3 control grid displacement.
//   k_disp   : dense (dy,dx) float2 field [256,1024] from 3x3 control points
//   k_wfilt  : spline prefilter along W (17-tap mirror FIR, f32 math), x ->
//              48 PAIR-PLANES: dword = fp16 pair (batch p, batch p+16)
//   k_hfilt  : prefilter along H in place, 13-tap, PACKED-f16 math
//              (v_pk_fma_f16, both batches per op — R14-proven pattern)
//   k_sample : 4x4 cubic gather; one thread -> (h,w) x batch-pair (b, b+16);
//              3 dwordx4 tap loads/row serve BOTH batches; pk-f16 x-reduce
//
// fp16 storage; pk-f16 math in k_sample x-reduction and hfilt FIR.

#define H_ 256
#define W_ 1024
#define B_ 32
#define RAD 8                // wfilt radius: |z|^9 trunc ~1e-4
#define RADH 6               // hfilt radius: trunc ~2e-3 (f16 chain kept short)
#define ROWF 3072            // W_*3 floats per (b,h) row of x
#define HW_ (H_ * W_)        // 262144 dwords per pair-plane

typedef float f4a __attribute__((ext_vector_type(4), aligned(4)));
typedef _Float16 h2 __attribute__((ext_vector_type(2)));

__device__ __forceinline__ h2 bch2(float d) { return __builtin_bit_cast(h2, d); }
__device__ __forceinline__ float bcf(h2 v) { return __builtin_bit_cast(float, v); }

__device__ __forceinline__ float b3f(float t) {
    float a = fabsf(t);
    if (a < 1.0f) return (4.0f - 6.0f * a * a + 3.0f * a * a * a) * (1.0f / 6.0f);
    if (a < 2.0f) { float s = 2.0f - a; return s * s * s * (1.0f / 6.0f); }
    return 0.0f;
}

__device__ __forceinline__ void cubw(float f, float* w) {
    float f2 = f * f, f3 = f2 * f;
    float om = 1.0f - f;
    w[0] = om * om * om * (1.0f / 6.0f);
    w[1] = (3.0f * f3 - 6.0f * f2 + 4.0f) * (1.0f / 6.0f);
    w[2] = (-3.0f * f3 + 3.0f * f2 + 3.0f * f + 1.0f) * (1.0f / 6.0f);
    w[3] = f3 * (1.0f / 6.0f);
}

__device__ __forceinline__ float clamp01(float v) {
    return fminf(fmaxf(v, 0.0f), 1.0f);
}

__device__ __forceinline__ float2 up2(float d) {
    return __half22float2(__builtin_bit_cast(__half2, d));
}
__device__ __forceinline__ float pk2(float a, float b) {
    return __builtin_bit_cast(float, __floats2half2_rn(a, b));
}

__device__ __forceinline__ void basis3(int i, int n, float& w0, float& w1, float& w2) {
    float u = (float)i * 2.0f / (float)(n - 1);
    int base = (int)floorf(u);
    w0 = w1 = w2 = 0.0f;
#pragma unroll
    for (int k = -1; k < 3; ++k) {
        int id = base + k;
        float bw = b3f(u - (float)id);
        int j = id < 0 ? -id : id;
        j &= 3;
        if (j == 3) j = 1;
        if (j == 0) w0 += bw; else if (j == 1) w1 += bw; else w2 += bw;
    }
}

// ---------------- kernel 0: displacement field (dy,dx) --------------------
__global__ __launch_bounds__(256) void k_disp(const float* __restrict__ disp,
                                              float2* __restrict__ dxy) {
    int idx = blockIdx.x * 256 + threadIdx.x;
    int h = idx >> 10, w = idx & 1023;

    const float A[3][3] = {{1.75f, -1.0f, 0.25f},
                           {-0.5f,  2.0f, -0.5f},
                           {0.25f, -1.0f, 1.75f}};
    float Ty[3][3], Tx[3][3];
#pragma unroll
    for (int i = 0; i < 3; ++i)
#pragma unroll
        for (int j = 0; j < 3; ++j) {
            float ty = 0.f, tx = 0.f;
#pragma unroll
            for (int k = 0; k < 3; ++k) {
                ty += A[i][k] * (5.0f * disp[k * 3 + j]);
                tx += A[i][k] * (5.0f * disp[9 + k * 3 + j]);
            }
            Ty[i][j] = ty; Tx[i][j] = tx;
        }
    float Cy[3][3], Cx[3][3];
#pragma unroll
    for (int i = 0; i < 3; ++i)
#pragma unroll
        for (int j = 0; j < 3; ++j) {
            float ty = 0.f, tx = 0.f;
#pragma unroll
            for (int k = 0; k < 3; ++k) {
                ty += Ty[i][k] * A[j][k];
                tx += Tx[i][k] * A[j][k];
            }
            Cy[i][j] = ty; Cx[i][j] = tx;
        }

    float rh0, rh1, rh2, rw0, rw1, rw2;
    basis3(h, H_, rh0, rh1, rh2);
    basis3(w, W_, rw0, rw1, rw2);
    float rh[3] = {rh0, rh1, rh2}, rw[3] = {rw0, rw1, rw2};

    float dy = 0.f, dx = 0.f;
#pragma unroll
    for (int i = 0; i < 3; ++i)
#pragma unroll
        for (int j = 0; j < 3; ++j) {
            dy += rh[i] * Cy[i][j] * rw[j];
            dx += rh[i] * Cx[i][j] * rw[j];
        }
    dxy[idx] = make_float2(dy, dx);
}

// ---------------- kernel 1: prefilter along W -> pair-planes --------------
// block bp = p*256 + h handles rows (p,h) AND (p+16,h); f32 math.
#define PLN 1040
__global__ __launch_bounds__(256) void k_wfilt(const float* __restrict__ x,
                                               float* __restrict__ pairP) {
    __shared__ float pl[6 * PLN];
    const int bp = blockIdx.x;           // p*256 + h, p in 0..15
    const int p = bp >> 8, h = bp & 255;
    const int t = threadIdx.x;

#pragma unroll
    for (int bi = 0; bi < 2; ++bi) {
        const float* row = x + ((size_t)(p + 16 * bi) * H_ + h) * ROWF;
        float4 v0 = *(const float4*)(row + 12 * t);
        float4 v1 = *(const float4*)(row + 12 * t + 4);
        float4 v2 = *(const float4*)(row + 12 * t + 8);
        float4 c0, c1, c2;
        c0.x = v0.x; c0.y = v0.w; c0.z = v1.z; c0.w = v2.y;
        c1.x = v0.y; c1.y = v1.x; c1.z = v1.w; c1.w = v2.z;
        c2.x = v0.z; c2.y = v1.y; c2.z = v2.x; c2.w = v2.w;
        *(float4*)(pl + (bi * 3 + 0) * PLN + 8 + 4 * t) = c0;
        *(float4*)(pl + (bi * 3 + 1) * PLN + 8 + 4 * t) = c1;
        *(float4*)(pl + (bi * 3 + 2) * PLN + 8 + 4 * t) = c2;
    }
    __syncthreads();

    if (t < 96) {                        // mirror halos: 6 rows x (8+8)
        int rb = t / 48, rem = t % 48;
        int c = rem >> 4, i = rem & 15;
        float* pp = pl + (rb * 3 + c) * PLN;
        if (i < 8) { int j = i + 1; pp[8 - j] = pp[8 + j]; }
        else { int r = i - 8; pp[1032 + r] = pp[1030 - r]; }
    }
    __syncthreads();

    float g[RAD + 1];
    g[0] = 1.7320508075688773f;
#pragma unroll
    for (int k = 1; k <= RAD; ++k) g[k] = g[k - 1] * (-0.26794919243112270647f);

    float res[2][3][4];
#pragma unroll
    for (int bi = 0; bi < 2; ++bi)
#pragma unroll
        for (int c = 0; c < 3; ++c) {
            const float* pp = pl + (bi * 3 + c) * PLN + 4 * t;
            float w[20];
#pragma unroll
            for (int i = 0; i < 5; ++i) {
                float4 v = *(const float4*)(pp + 4 * i);
                w[4 * i] = v.x; w[4 * i + 1] = v.y;
                w[4 * i + 2] = v.z; w[4 * i + 3] = v.w;
            }
#pragma unroll
            for (int j = 0; j < 4; ++j) {
                float a = g[0] * w[j + 8];
#pragma unroll
                for (int k = 1; k <= 8; ++k)
                    a += g[k] * (w[j + 8 - k] + w[j + 8 + k]);
                res[bi][c][j] = a;
            }
        }

#pragma unroll
    for (int c = 0; c < 3; ++c) {
        float4 o;
        o.x = pk2(res[0][c][0], res[1][c][0]);
        o.y = pk2(res[0][c][1], res[1][c][1]);
        o.z = pk2(res[0][c][2], res[1][c][2]);
        o.w = pk2(res[0][c][3], res[1][c][3]);
        *(float4*)(pairP + (size_t)(p * 3 + c) * HW_ + (size_t)h * W_ + 4 * t) = o;
    }
}

// ---------------- kernel 2: prefilter along H, pk-f16 math ----------------
// grid (32, 48): 48 identical pair-planes. 13-tap (RADH=6), v_pk_fma_f16
// processes both batch-halves per op; store is a direct bitcast (no repack).
#define TSTR 40
__global__ __launch_bounds__(256) void k_hfilt(float* __restrict__ pairP) {
    __shared__ float tile[H_ * TSTR];   // 40 KiB
    const int t = threadIdx.x;
    float* src = pairP + (size_t)blockIdx.y * HW_ + blockIdx.x * 32;

#pragma unroll
    for (int it = 0; it < 8; ++it) {
        int idx = t + it * 256;          // 0..2047 float4s
        int r = idx >> 3, seg = idx & 7;
        *(float4*)(tile + r * TSTR + seg * 4) =
            *(const float4*)(src + (size_t)r * W_ + seg * 4);
    }
    __syncthreads();

    float g[RADH + 1];
    g[0] = 1.7320508075688773f;
#pragma unroll
    for (int k = 1; k <= RADH; ++k) g[k] = g[k - 1] * (-0.26794919243112270647f);
    h2 gh[RADH + 1];
#pragma unroll
    for (int k = 0; k <= RADH; ++k) gh[k] = bch2(pk2(g[k], g[k]));

    const int cg = t & 7;          // dword4 column group
    const int prow = t >> 3;       // 0..31
    const int p0 = prow * 8;

    const h2 zz = bch2(0.f);
    h2 acc[8][4];
#pragma unroll
    for (int j = 0; j < 8; ++j)
#pragma unroll
        for (int q = 0; q < 4; ++q) acc[j][q] = zz;

#pragma unroll
    for (int r = 0; r < 8 + 2 * RADH; ++r) {   // 20 rows
        int hh = p0 - RADH + r;
        int m1 = hh < 0 ? -hh : hh;
        int m2 = 2 * (H_ - 1) - hh;
        int mp = m1 < m2 ? m1 : m2;
        float4 v = *(const float4*)(tile + mp * TSTR + cg * 4);
        h2 hv0 = bch2(v.x), hv1 = bch2(v.y), hv2 = bch2(v.z), hv3 = bch2(v.w);
#pragma unroll
        for (int j = 0; j < 8; ++j) {
            const int d = r - RADH - j;
            if (d >= -RADH && d <= RADH) {
                const h2 wgt = gh[d < 0 ? -d : d];
                acc[j][0] += wgt * hv0;
                acc[j][1] += wgt * hv1;
                acc[j][2] += wgt * hv2;
                acc[j][3] += wgt * hv3;
            }
        }
    }

#pragma unroll
    for (int j = 0; j < 8; ++j) {
        float4 o;
        o.x = bcf(acc[j][0]);
        o.y = bcf(acc[j][1]);
        o.z = bcf(acc[j][2]);
        o.w = bcf(acc[j][3]);
        *(float4*)(src + (size_t)(p0 + j) * W_ + cg * 4) = o;
    }
}

// ---------------- kernel 3: 4x4 cubic gather, batch-pair/thread -----------
// grid (1024, 16): thread owns (h,w) for batches (b0, b0+16). Each tap row:
// 3 unaligned dwordx4 loads serve both batches & all channels.
__global__ __launch_bounds__(256) void k_sample(const float* __restrict__ pairP,
                                                const float2* __restrict__ dxy,
                                                float* __restrict__ out) {
    __shared__ float os[2][768];
    const int t = threadIdx.x;
    const int hw = blockIdx.x * 256 + t;
    const int b0 = blockIdx.y;            // 0..15; pair (b0, b0+16)
    const int h = hw >> 10, w = hw & 1023;

    float2 d = dxy[hw];
    float cy = (float)h + d.x;
    float cx = (float)w + d.y;
    float byf = floorf(cy), bxf = floorf(cx);
    int by = (int)byf, bx = (int)bxf;
    float wy[4], wx[4];
    cubw(cy - byf, wy);
    cubw(cx - bxf, wx);

    int iyW[4];
#pragma unroll
    for (int r = 0; r < 4; ++r)
        iyW[r] = min(max(by - 1 + r, 0), H_ - 1) * W_;

    const float* pc0 = pairP + (size_t)(b0 * 3) * HW_;
    const float* pc1 = pc0 + HW_;
    const float* pc2 = pc1 + HW_;

    float sA0 = 0.f, sA1 = 0.f, sA2 = 0.f;
    float sB0 = 0.f, sB1 = 0.f, sB2 = 0.f;

    if (bx >= 1 && bx <= W_ - 3) {
        const h2 w0 = bch2(pk2(wx[0], wx[0]));
        const h2 w1 = bch2(pk2(wx[1], wx[1]));
        const h2 w2 = bch2(pk2(wx[2], wx[2]));
        const h2 w3 = bch2(pk2(wx[3], wx[3]));

#pragma unroll
        for (int r = 0; r < 4; ++r) {
            const int o = iyW[r] + bx - 1;
            f4a v0 = *(const f4a*)(pc0 + o);
            f4a v1 = *(const f4a*)(pc1 + o);
            f4a v2 = *(const f4a*)(pc2 + o);
            const float wyr = wy[r];
            h2 a0 = bch2(v0.x) * w0 + bch2(v0.y) * w1;
            a0 = a0 + bch2(v0.z) * w2 + bch2(v0.w) * w3;
            h2 a1 = bch2(v1.x) * w0 + bch2(v1.y) * w1;
            a1 = a1 + bch2(v1.z) * w2 + bch2(v1.w) * w3;
            h2 a2 = bch2(v2.x) * w0 + bch2(v2.y) * w1;
            a2 = a2 + bch2(v2.z) * w2 + bch2(v2.w) * w3;
            float2 u0 = up2(bcf(a0));
            float2 u1 = up2(bcf(a1));
            float2 u2 = up2(bcf(a2));
            sA0 = fmaf(wyr, u0.x, sA0); sB0 = fmaf(wyr, u0.y, sB0);
            sA1 = fmaf(wyr, u1.x, sA1); sB1 = fmaf(wyr, u1.y, sB1);
            sA2 = fmaf(wyr, u2.x, sA2); sB2 = fmaf(wyr, u2.y, sB2);
        }
    } else {
        int ix4[4];
#pragma unroll
        for (int k = 0; k < 4; ++k) ix4[k] = min(max(bx - 1 + k, 0), W_ - 1);
#pragma unroll
        for (int r = 0; r < 4; ++r) {
            float wyr = wy[r];
#pragma unroll
            for (int k = 0; k < 4; ++k) {
                float wk = wyr * wx[k];
                int o = iyW[r] + ix4[k];
                float2 u0 = up2(pc0[o]);
                float2 u1 = up2(pc1[o]);
                float2 u2 = up2(pc2[o]);
                sA0 += wk * u0.x; sB0 += wk * u0.y;
                sA1 += wk * u1.x; sB1 += wk * u1.y;
                sA2 += wk * u2.x; sB2 += wk * u2.y;
            }
        }
    }

    os[0][3 * t + 0] = clamp01(sA0);
    os[0][3 * t + 1] = clamp01(sA1);
    os[0][3 * t + 2] = clamp01(sA2);
    os[1][3 * t + 0] = clamp01(sB0);
    os[1][3 * t + 1] = clamp01(sB1);
    os[1][3 * t + 2] = clamp01(sB2);
    __syncthreads();

    if (t < 192) {
        float4 vA = *(const float4*)(&os[0][0] + 4 * t);
        float4 vB = *(const float4*)(&os[1][0] + 4 * t);
        float* oA = out + ((size_t)b0 * HW_ + (size_t)blockIdx.x * 256) * 3;
        float* oB = out + ((size_t)(b0 + 16) * HW_ + (size_t)blockIdx.x * 256) * 3;
        *(float4*)(oA + 4 * t) = vA;
        *(float4*)(oB + 4 * t) = vB;
    }
}

extern "C" void kernel_launch(void* const* d_in, const int* in_sizes, int n_in,
                              void* d_out, int out_size, void* d_ws, size_t ws_size,
                              hipStream_t stream) {
    const float* x = (const float*)d_in[0];      // [32,256,1024,3]
    const float* disp = (const float*)d_in[1];   // [2,3,3]
    float* out = (float*)d_out;

    char* ws = (char*)d_ws;
    float* pairP = (float*)ws;                     // 48 MiB: 48 pair-planes
    float2* dxy = (float2*)(ws + 50331648ull);     // 2 MiB

    k_disp<<<dim3(HW_ / 256), dim3(256), 0, stream>>>(disp, dxy);

    k_wfilt<<<dim3((B_ / 2) * H_), dim3(256), 0, stream>>>(x, pairP);

    k_hfilt<<<dim3(32, 48), dim3(256), 0, stream>>>(pairP);

    k_sample<<<dim3(HW_ / 256, B_ / 2), dim3(256), 0, stream>>>(pairP, dxy, out);
}